// Round 1
// baseline (1186.403 us; speedup 1.0000x reference)
//
#include <hip/hip_runtime.h>
#include <math.h>

#define NEG_SLOPE 0.2f

static inline int idiv(int a, int b) { return (a + b - 1) / b; }

// ---------------- CSR build ----------------

__global__ void zero_int_kernel(int* p, int n) {
    int i = blockIdx.x * blockDim.x + threadIdx.x;
    if (i < n) p[i] = 0;
}

__global__ void hist_kernel(const int* __restrict__ dst, int E, int N, int* __restrict__ cnt) {
    int i = blockIdx.x * blockDim.x + threadIdx.x;
    if (i >= E + N) return;
    int d = (i < E) ? dst[i] : (i - E);
    atomicAdd(&cnt[d], 1);
}

// single-block inclusive scan over N counts -> row_ptr[N+1], woff = exclusive copy
__global__ void scan_kernel(const int* __restrict__ cnt, int* __restrict__ row_ptr,
                            int* __restrict__ wofs, int N) {
    __shared__ int wsum[4];
    __shared__ int carry_s;
    int tid = threadIdx.x, lane = tid & 63, wid = tid >> 6;
    if (tid == 0) { carry_s = 0; row_ptr[0] = 0; }
    __syncthreads();
    for (int base = 0; base < N; base += 256) {
        int i = base + tid;
        int v = (i < N) ? cnt[i] : 0;
        int incl = v;
        #pragma unroll
        for (int off = 1; off < 64; off <<= 1) {
            int t = __shfl_up(incl, off);
            if (lane >= off) incl += t;
        }
        if (lane == 63) wsum[wid] = incl;
        __syncthreads();
        int w0 = wsum[0], w1 = wsum[1], w2 = wsum[2], w3 = wsum[3];
        int wbase = (wid > 0 ? w0 : 0) + (wid > 1 ? w1 : 0) + (wid > 2 ? w2 : 0);
        int tot = w0 + w1 + w2 + w3;
        int carry = carry_s;
        incl += wbase;
        if (i < N) { row_ptr[i + 1] = carry + incl; wofs[i] = carry + incl - v; }
        __syncthreads();
        if (tid == 0) carry_s = carry + tot;
        __syncthreads();
    }
}

__global__ void scatter_kernel(const int* __restrict__ src, const int* __restrict__ dst,
                               int E, int N, int* __restrict__ wofs, int* __restrict__ sorted_src) {
    int i = blockIdx.x * blockDim.x + threadIdx.x;
    if (i >= E + N) return;
    int d, s;
    if (i < E) { d = dst[i]; s = src[i]; } else { d = i - E; s = d; }
    int pos = atomicAdd(&wofs[d], 1);
    sorted_src[pos] = s;
}

// ---------------- GEMM: C[N,256] = A[N,K] @ W[K,256], for both Wl and Wr ----------------
// 128x64 tile, 256 threads, 8x4 microtile. A staged transposed for b128 LDS reads.

__global__ __launch_bounds__(256) void gemm_dual_kernel(
    const float* __restrict__ A, int N, int K,
    const float* __restrict__ Wl, const float* __restrict__ Wr,
    float* __restrict__ Cl, float* __restrict__ Cr) {
    const int M = 256;
    __shared__ float At[16][136];  // At[k][r], r in [0,128)
    __shared__ float Bs[16][68];
    int by = blockIdx.y;
    const float* __restrict__ W;
    float* __restrict__ C;
    if (by < 4) { W = Wl; C = Cl; } else { W = Wr; C = Cr; by -= 4; }
    const int row0 = blockIdx.x * 128;
    const int col0 = by * 64;
    const int tid = threadIdx.x;
    const int tx = tid & 15;  // col group
    const int ty = tid >> 4;  // row group 0..15
    float acc[8][4];
    #pragma unroll
    for (int i = 0; i < 8; i++)
        #pragma unroll
        for (int j = 0; j < 4; j++) acc[i][j] = 0.f;

    for (int k0 = 0; k0 < K; k0 += 16) {
        {
            int r = tid >> 1;        // 0..127
            int cb = (tid & 1) * 8;  // 0 or 8
            int row = row0 + r;
            float4 v0, v1;
            if (row < N) {
                v0 = *(const float4*)(A + (size_t)row * K + k0 + cb);
                v1 = *(const float4*)(A + (size_t)row * K + k0 + cb + 4);
            } else {
                v0 = make_float4(0.f, 0.f, 0.f, 0.f);
                v1 = v0;
            }
            At[cb + 0][r] = v0.x; At[cb + 1][r] = v0.y;
            At[cb + 2][r] = v0.z; At[cb + 3][r] = v0.w;
            At[cb + 4][r] = v1.x; At[cb + 5][r] = v1.y;
            At[cb + 6][r] = v1.z; At[cb + 7][r] = v1.w;
        }
        {
            int r = tid >> 4;
            int c = (tid & 15) * 4;
            float4 v = *(const float4*)(W + (size_t)(k0 + r) * M + col0 + c);
            *(float4*)&Bs[r][c] = v;
        }
        __syncthreads();
        #pragma unroll
        for (int k = 0; k < 16; ++k) {
            float4 a0 = *(const float4*)&At[k][ty * 8];
            float4 a1 = *(const float4*)&At[k][ty * 8 + 4];
            float4 b = *(const float4*)&Bs[k][tx * 4];
            float av[8] = {a0.x, a0.y, a0.z, a0.w, a1.x, a1.y, a1.z, a1.w};
            float bv[4] = {b.x, b.y, b.z, b.w};
            #pragma unroll
            for (int i = 0; i < 8; i++)
                #pragma unroll
                for (int j = 0; j < 4; j++) acc[i][j] += av[i] * bv[j];
        }
        __syncthreads();
    }
    #pragma unroll
    for (int i = 0; i < 8; i++) {
        int row = row0 + ty * 8 + i;
        if (row < N) {
            float4 v = make_float4(acc[i][0], acc[i][1], acc[i][2], acc[i][3]);
            *(float4*)(C + (size_t)row * M + col0 + tx * 4) = v;
        }
    }
}

// ---------------- small GEMM for layer 4: C[N,16] = A[N,256] @ W[256,16] ----------------

__global__ __launch_bounds__(256) void gemm_small_kernel(
    const float* __restrict__ A, int N,
    const float* __restrict__ Wl, const float* __restrict__ Wr,
    float* __restrict__ Cl, float* __restrict__ Cr) {
    const int K = 256, M = 16;
    __shared__ float As[16][260];
    const float* __restrict__ W = (blockIdx.y == 0) ? Wl : Wr;
    float* __restrict__ C = (blockIdx.y == 0) ? Cl : Cr;
    int row0 = blockIdx.x * 16;
    int tid = threadIdx.x;
    {
        int r = tid >> 4;
        int c = (tid & 15) * 16;
        int row = row0 + r;
        #pragma unroll
        for (int u = 0; u < 4; ++u) {
            float4 v = (row < N) ? *(const float4*)(A + (size_t)row * K + c + u * 4)
                                 : make_float4(0.f, 0.f, 0.f, 0.f);
            *(float4*)&As[r][c + u * 4] = v;
        }
    }
    __syncthreads();
    int r = tid >> 4;
    int col = tid & 15;
    float acc = 0.f;
    #pragma unroll 8
    for (int k = 0; k < K; ++k) acc += As[r][k] * W[k * M + col];
    int row = row0 + r;
    if (row < N) C[(size_t)row * M + col] = acc;
}

// ---------------- edge kernel, H=8 D=32 (HD=256): one wave per dst node ----------------

__global__ __launch_bounds__(256) void edge_h8_kernel(
    const float* __restrict__ xl, const float* __restrict__ xr,
    const int* __restrict__ row_ptr, const int* __restrict__ sorted_src,
    const float* __restrict__ att, const float* __restrict__ bias,
    float* __restrict__ hout, int N, int apply_elu) {
    int wave = threadIdx.x >> 6;
    int lane = threadIdx.x & 63;
    int n = blockIdx.x * 4 + wave;
    if (n >= N) return;
    const int HD = 256;
    float4 xrv = *(const float4*)(xr + (size_t)n * HD + lane * 4);
    float4 attv = *(const float4*)(att + lane * 4);
    float m = -INFINITY, s = 0.f;
    float a0 = 0.f, a1 = 0.f, a2 = 0.f, a3 = 0.f;
    int beg = row_ptr[n], end = row_ptr[n + 1];
    for (int i = beg; i < end; ++i) {
        int sidx = sorted_src[i];
        float4 xv = *(const float4*)(xl + (size_t)sidx * HD + lane * 4);
        float g0 = xv.x + xrv.x, g1 = xv.y + xrv.y, g2 = xv.z + xrv.z, g3 = xv.w + xrv.w;
        float l0 = g0 > 0.f ? g0 : NEG_SLOPE * g0;
        float l1 = g1 > 0.f ? g1 : NEG_SLOPE * g1;
        float l2 = g2 > 0.f ? g2 : NEG_SLOPE * g2;
        float l3 = g3 > 0.f ? g3 : NEG_SLOPE * g3;
        float p = attv.x * l0 + attv.y * l1 + attv.z * l2 + attv.w * l3;
        p += __shfl_xor(p, 1);
        p += __shfl_xor(p, 2);
        p += __shfl_xor(p, 4);  // now p = e for head (lane>>3), replicated on its 8 lanes
        float mn = fmaxf(m, p);
        float cf = __expf(m - mn);   // exp(-inf)=0 on first edge
        float pe = __expf(p - mn);
        s = s * cf + pe;
        a0 = a0 * cf + pe * xv.x;
        a1 = a1 * cf + pe * xv.y;
        a2 = a2 * cf + pe * xv.z;
        a3 = a3 * cf + pe * xv.w;
        m = mn;
    }
    float inv = 1.f / (s + 1e-16f);
    float4 bv = *(const float4*)(bias + lane * 4);
    float o0 = a0 * inv + bv.x;
    float o1 = a1 * inv + bv.y;
    float o2 = a2 * inv + bv.z;
    float o3 = a3 * inv + bv.w;
    if (apply_elu) {
        o0 = o0 > 0.f ? o0 : __expf(o0) - 1.f;
        o1 = o1 > 0.f ? o1 : __expf(o1) - 1.f;
        o2 = o2 > 0.f ? o2 : __expf(o2) - 1.f;
        o3 = o3 > 0.f ? o3 : __expf(o3) - 1.f;
    }
    *(float4*)(hout + (size_t)n * HD + lane * 4) = make_float4(o0, o1, o2, o3);
}

// ---------------- edge kernel layer 4, H=1 D=16, fused log_softmax -> d_out ----------------

__global__ __launch_bounds__(256) void edge_h1_kernel(
    const float* __restrict__ xl, const float* __restrict__ xr,
    const int* __restrict__ row_ptr, const int* __restrict__ sorted_src,
    const float* __restrict__ att, const float* __restrict__ bias,
    float* __restrict__ out, int N) {
    int wave = threadIdx.x >> 6;
    int lane = threadIdx.x & 63;
    int n = blockIdx.x * 4 + wave;
    if (n >= N) return;
    int d = lane & 15;  // lanes replicate the 16 dims 4x (uniform, no divergence)
    float xrv = xr[(size_t)n * 16 + d];
    float attv = att[d];
    float m = -INFINITY, s = 0.f, acc = 0.f;
    int beg = row_ptr[n], end = row_ptr[n + 1];
    for (int i = beg; i < end; ++i) {
        int sidx = sorted_src[i];
        float xv = xl[(size_t)sidx * 16 + d];
        float g = xv + xrv;
        float l = g > 0.f ? g : NEG_SLOPE * g;
        float p = attv * l;
        p += __shfl_xor(p, 1);
        p += __shfl_xor(p, 2);
        p += __shfl_xor(p, 4);
        p += __shfl_xor(p, 8);
        float mn = fmaxf(m, p);
        float cf = __expf(m - mn);
        float pe = __expf(p - mn);
        s = s * cf + pe;
        acc = acc * cf + pe * xv;
        m = mn;
    }
    float v = acc / (s + 1e-16f) + bias[d];
    // log_softmax over the 16 dims (within each aligned 16-lane group)
    float mx = v;
    mx = fmaxf(mx, __shfl_xor(mx, 1));
    mx = fmaxf(mx, __shfl_xor(mx, 2));
    mx = fmaxf(mx, __shfl_xor(mx, 4));
    mx = fmaxf(mx, __shfl_xor(mx, 8));
    float ex = __expf(v - mx);
    float se = ex;
    se += __shfl_xor(se, 1);
    se += __shfl_xor(se, 2);
    se += __shfl_xor(se, 4);
    se += __shfl_xor(se, 8);
    float res = v - mx - __logf(se);
    if (lane < 16) out[(size_t)n * 16 + d] = res;
}

// ---------------- launch ----------------

extern "C" void kernel_launch(void* const* d_in, const int* in_sizes, int n_in,
                              void* d_out, int out_size, void* d_ws, size_t ws_size,
                              hipStream_t stream) {
    const float* x    = (const float*)d_in[0];
    const int*   ei   = (const int*)d_in[1];
    const float* Wl1  = (const float*)d_in[2];
    const float* Wr1  = (const float*)d_in[3];
    const float* att1 = (const float*)d_in[4];
    const float* b1   = (const float*)d_in[5];
    const float* Wl2  = (const float*)d_in[6];
    const float* Wr2  = (const float*)d_in[7];
    const float* att2 = (const float*)d_in[8];
    const float* b2   = (const float*)d_in[9];
    const float* Wl3  = (const float*)d_in[10];
    const float* Wr3  = (const float*)d_in[11];
    const float* att3 = (const float*)d_in[12];
    const float* b3   = (const float*)d_in[13];
    const float* Wl4  = (const float*)d_in[14];
    const float* Wr4  = (const float*)d_in[15];
    const float* att4 = (const float*)d_in[16];
    const float* b4   = (const float*)d_in[17];

    const int N = in_sizes[0] / 128;
    const int E = in_sizes[1] / 2;
    const int* src = ei;
    const int* dst = ei + E;
    const int Etot = E + N;

    char* wsb = (char*)d_ws;
    size_t off = 0;
    auto alloc = [&](size_t bytes) -> void* {
        void* p = wsb + off;
        off += (bytes + 255) & ~(size_t)255;
        return p;
    };
    float* xl  = (float*)alloc((size_t)N * 256 * 4);
    float* xr  = (float*)alloc((size_t)N * 256 * 4);
    float* h   = (float*)alloc((size_t)N * 256 * 4);
    int*   cnt = (int*)alloc((size_t)N * 4);
    int*   wof = (int*)alloc((size_t)N * 4);
    int*   rp  = (int*)alloc((size_t)(N + 1) * 4);
    int*   ss  = (int*)alloc((size_t)Etot * 4);

    // CSR build (recomputed every call; deterministic counts)
    zero_int_kernel<<<idiv(N, 256), 256, 0, stream>>>(cnt, N);
    hist_kernel<<<idiv(Etot, 256), 256, 0, stream>>>(dst, E, N, cnt);
    scan_kernel<<<1, 256, 0, stream>>>(cnt, rp, wof, N);
    scatter_kernel<<<idiv(Etot, 256), 256, 0, stream>>>(src, dst, E, N, wof, ss);

    dim3 gg(idiv(N, 128), 8);
    // layer 1 (K=128)
    gemm_dual_kernel<<<gg, 256, 0, stream>>>(x, N, 128, Wl1, Wr1, xl, xr);
    edge_h8_kernel<<<idiv(N, 4), 256, 0, stream>>>(xl, xr, rp, ss, att1, b1, h, N, 1);
    // layer 2
    gemm_dual_kernel<<<gg, 256, 0, stream>>>(h, N, 256, Wl2, Wr2, xl, xr);
    edge_h8_kernel<<<idiv(N, 4), 256, 0, stream>>>(xl, xr, rp, ss, att2, b2, h, N, 1);
    // layer 3
    gemm_dual_kernel<<<gg, 256, 0, stream>>>(h, N, 256, Wl3, Wr3, xl, xr);
    edge_h8_kernel<<<idiv(N, 4), 256, 0, stream>>>(xl, xr, rp, ss, att3, b3, h, N, 1);
    // layer 4 (M=16) + fused log_softmax
    gemm_small_kernel<<<dim3(idiv(N, 16), 2), 256, 0, stream>>>(h, N, Wl4, Wr4, xl, xr);
    edge_h1_kernel<<<idiv(N, 4), 256, 0, stream>>>(xl, xr, rp, ss, att4, b4, (float*)d_out, N);
}

// Round 2
// 736.782 us; speedup vs baseline: 1.6102x; 1.6102x over previous
//
#include <hip/hip_runtime.h>
#include <math.h>

#define NEG_SLOPE 0.2f

typedef _Float16 f16;
typedef _Float16 f16x4 __attribute__((ext_vector_type(4)));
typedef _Float16 f16x8 __attribute__((ext_vector_type(8)));
typedef float f32x4 __attribute__((ext_vector_type(4)));

static inline int idiv(int a, int b) { return (a + b - 1) / b; }

// ---------------- conversions ----------------

__global__ void conv_f32_f16_kernel(const float* __restrict__ in, f16* __restrict__ out, int n) {
    int i = (blockIdx.x * blockDim.x + threadIdx.x) * 4;
    if (i + 3 < n) {
        float4 v = *(const float4*)(in + i);
        f16x4 o = {(f16)v.x, (f16)v.y, (f16)v.z, (f16)v.w};
        *(f16x4*)(out + i) = o;
    } else {
        for (int j = i; j < n; ++j) out[j] = (f16)in[j];
    }
}

// W [K][256] f32 -> Wt [256][K] f16
__global__ __launch_bounds__(256) void convT_kernel(const float* __restrict__ W,
                                                    f16* __restrict__ Wt, int K) {
    __shared__ float tbl[32][33];
    int bk = blockIdx.x * 32, bc = blockIdx.y * 32;
    int tx = threadIdx.x & 31, ty = threadIdx.x >> 5;  // ty 0..7
    #pragma unroll
    for (int i = 0; i < 32; i += 8) tbl[ty + i][tx] = W[(size_t)(bk + ty + i) * 256 + bc + tx];
    __syncthreads();
    #pragma unroll
    for (int i = 0; i < 32; i += 8)
        Wt[(size_t)(bc + ty + i) * K + bk + tx] = (f16)tbl[tx][ty + i];
}

// ---------------- CSR build ----------------

__global__ void zero_int_kernel(int* p, int n) {
    int i = blockIdx.x * blockDim.x + threadIdx.x;
    if (i < n) p[i] = 0;
}

__global__ void hist_kernel(const int* __restrict__ dst, int E, int N, int* __restrict__ cnt) {
    int i = blockIdx.x * blockDim.x + threadIdx.x;
    if (i >= E + N) return;
    int d = (i < E) ? dst[i] : (i - E);
    atomicAdd(&cnt[d], 1);
}

// single-block scan, 4 elems/thread
__global__ void scan_kernel(const int* __restrict__ cnt, int* __restrict__ row_ptr,
                            int* __restrict__ wofs, int N) {
    __shared__ int wsum[4];
    __shared__ int carry_s;
    int tid = threadIdx.x, lane = tid & 63, wid = tid >> 6;
    if (tid == 0) { carry_s = 0; row_ptr[0] = 0; }
    __syncthreads();
    for (int base = 0; base < N; base += 1024) {
        int i0 = base + tid * 4;
        int v0 = (i0 + 0 < N) ? cnt[i0 + 0] : 0;
        int v1 = (i0 + 1 < N) ? cnt[i0 + 1] : 0;
        int v2 = (i0 + 2 < N) ? cnt[i0 + 2] : 0;
        int v3 = (i0 + 3 < N) ? cnt[i0 + 3] : 0;
        int tsum = v0 + v1 + v2 + v3;
        int incl = tsum;
        #pragma unroll
        for (int off = 1; off < 64; off <<= 1) {
            int t = __shfl_up(incl, off);
            if (lane >= off) incl += t;
        }
        if (lane == 63) wsum[wid] = incl;
        __syncthreads();
        int w0 = wsum[0], w1 = wsum[1], w2 = wsum[2], w3 = wsum[3];
        int wbase = (wid > 0 ? w0 : 0) + (wid > 1 ? w1 : 0) + (wid > 2 ? w2 : 0);
        int tot = w0 + w1 + w2 + w3;
        int carry = carry_s;
        int pre = carry + wbase + incl - tsum;
        int p1 = pre + v0, p2 = p1 + v1, p3 = p2 + v2, p4 = p3 + v3;
        if (i0 + 0 < N) { wofs[i0 + 0] = pre; row_ptr[i0 + 1] = p1; }
        if (i0 + 1 < N) { wofs[i0 + 1] = p1;  row_ptr[i0 + 2] = p2; }
        if (i0 + 2 < N) { wofs[i0 + 2] = p2;  row_ptr[i0 + 3] = p3; }
        if (i0 + 3 < N) { wofs[i0 + 3] = p3;  row_ptr[i0 + 4] = p4; }
        __syncthreads();
        if (tid == 0) carry_s = carry + tot;
        __syncthreads();
    }
}

__global__ void scatter_kernel(const int* __restrict__ src, const int* __restrict__ dst,
                               int E, int N, int* __restrict__ wofs, int* __restrict__ sorted_src) {
    int i = blockIdx.x * blockDim.x + threadIdx.x;
    if (i >= E + N) return;
    int d, s;
    if (i < E) { d = dst[i]; s = src[i]; } else { d = i - E; s = d; }
    int pos = atomicAdd(&wofs[d], 1);
    sorted_src[pos] = s;
}

// ---------------- f16 MFMA GEMM: C[N,256] = A[N,K] @ W[K,256], dual (Wl,Wr) ----------------
// Wt is W transposed [256][K] f16. Tile 128x128, BK=64, 4 waves (2x2), wave = 64x64.
// LDS fragment-major: chunk[g][r] holds 8 f16 (k = g*8..g*8+7) of row/col r -> all ds ops
// are wave-contiguous b128 (no bank conflicts). A and B use the same (g,j)->k map, so the
// MFMA result is invariant to the exact HW k-permutation (bijection argument).

__global__ __launch_bounds__(256) void gemm16_dual(
    const f16* __restrict__ A, int N, int K,
    const f16* __restrict__ Wtl, const f16* __restrict__ Wtr,
    f16* __restrict__ Cl, f16* __restrict__ Cr) {
    __shared__ f16 lds[2 * 8 * 128 * 8];  // 32 KB
    f16x8* Asp = (f16x8*)lds;              // [g*128 + r], g=0..7 (k=g*8), r=0..127
    f16x8* Bsp = (f16x8*)(lds + 8 * 128 * 8);
    const int by = blockIdx.y;
    const f16* __restrict__ Wt = (by >> 1) ? Wtr : Wtl;
    f16* __restrict__ C = (by >> 1) ? Cr : Cl;
    const int col0 = (by & 1) * 128;
    const int row0 = blockIdx.x * 128;
    const int t = threadIdx.x;
    const int lane = t & 63;
    const int wid = t >> 6;
    const int wr = (wid >> 1) * 64, wc = (wid & 1) * 64;
    const int lg = lane >> 4, lr = lane & 15;

    f32x4 acc[4][4];
    #pragma unroll
    for (int m = 0; m < 4; ++m)
        #pragma unroll
        for (int n = 0; n < 4; ++n) acc[m][n] = (f32x4){0.f, 0.f, 0.f, 0.f};

    const int r_st = t >> 1;         // 0..127
    const int ks_st = (t & 1) * 32;  // 0 or 32
    const f16x8 zv = {0, 0, 0, 0, 0, 0, 0, 0};

    for (int k0 = 0; k0 < K; k0 += 64) {
        {
            const f16* srcA = A + (size_t)(row0 + r_st) * K + k0 + ks_st;
            const bool ok = (row0 + r_st) < N;
            #pragma unroll
            for (int u = 0; u < 4; ++u) {
                f16x8 v = ok ? *(const f16x8*)(srcA + u * 8) : zv;
                Asp[(ks_st / 8 + u) * 128 + r_st] = v;
            }
            const f16* srcB = Wt + (size_t)(col0 + r_st) * K + k0 + ks_st;
            #pragma unroll
            for (int u = 0; u < 4; ++u) {
                f16x8 v = *(const f16x8*)(srcB + u * 8);
                Bsp[(ks_st / 8 + u) * 128 + r_st] = v;
            }
        }
        __syncthreads();
        #pragma unroll
        for (int s = 0; s < 2; ++s) {
            f16x8 af[4], bf[4];
            #pragma unroll
            for (int m = 0; m < 4; ++m) af[m] = Asp[(s * 4 + lg) * 128 + wr + m * 16 + lr];
            #pragma unroll
            for (int n = 0; n < 4; ++n) bf[n] = Bsp[(s * 4 + lg) * 128 + wc + n * 16 + lr];
            #pragma unroll
            for (int m = 0; m < 4; ++m)
                #pragma unroll
                for (int n = 0; n < 4; ++n)
                    acc[m][n] = __builtin_amdgcn_mfma_f32_16x16x32_f16(af[m], bf[n], acc[m][n], 0, 0, 0);
        }
        __syncthreads();
    }
    // epilogue: C/D layout col=lane&15, row=(lane>>4)*4+reg  [verified m89]
    #pragma unroll
    for (int m = 0; m < 4; ++m) {
        int row_b = row0 + wr + m * 16 + lg * 4;
        #pragma unroll
        for (int reg = 0; reg < 4; ++reg) {
            int row = row_b + reg;
            if (row < N) {
                #pragma unroll
                for (int n = 0; n < 4; ++n)
                    C[(size_t)row * 256 + col0 + wc + n * 16 + lr] = (f16)acc[m][n][reg];
            }
        }
    }
}

// ---------------- small GEMM layer 4: C[N,16] = A16[N,256] @ W[256,16] ----------------

__global__ __launch_bounds__(256) void gemm_small16(
    const f16* __restrict__ A, int N,
    const float* __restrict__ Wl, const float* __restrict__ Wr,
    float* __restrict__ Cl, float* __restrict__ Cr) {
    const int K = 256, M = 16;
    __shared__ float As[16][260];
    const float* __restrict__ W = (blockIdx.y == 0) ? Wl : Wr;
    float* __restrict__ C = (blockIdx.y == 0) ? Cl : Cr;
    int row0 = blockIdx.x * 16;
    int tid = threadIdx.x;
    {
        int r = tid >> 4;
        int c = (tid & 15) * 16;
        int row = row0 + r;
        if (row < N) {
            f16x8 v0 = *(const f16x8*)(A + (size_t)row * K + c);
            f16x8 v1 = *(const f16x8*)(A + (size_t)row * K + c + 8);
            #pragma unroll
            for (int j = 0; j < 8; ++j) { As[r][c + j] = (float)v0[j]; As[r][c + 8 + j] = (float)v1[j]; }
        } else {
            #pragma unroll
            for (int j = 0; j < 16; ++j) As[r][c + j] = 0.f;
        }
    }
    __syncthreads();
    int r = tid >> 4;
    int col = tid & 15;
    float acc = 0.f;
    #pragma unroll 8
    for (int k = 0; k < K; ++k) acc += As[r][k] * W[k * M + col];
    int row = row0 + r;
    if (row < N) C[(size_t)row * M + col] = acc;
}

// ---------------- edge kernel, H=8 D=32 (HD=256), f16 activations ----------------

__global__ __launch_bounds__(256) void edge_h8_f16(
    const f16* __restrict__ xl, const f16* __restrict__ xr,
    const int* __restrict__ rp, const int* __restrict__ ss,
    const float* __restrict__ att, const float* __restrict__ bias,
    f16* __restrict__ hout, int N, int apply_elu) {
    int wave = threadIdx.x >> 6;
    int lane = threadIdx.x & 63;
    int n = blockIdx.x * 4 + wave;
    if (n >= N) return;
    const int HD = 256;
    f16x4 xrr = *(const f16x4*)(xr + (size_t)n * HD + lane * 4);
    float xr0 = (float)xrr[0], xr1 = (float)xrr[1], xr2 = (float)xrr[2], xr3 = (float)xrr[3];
    float4 attv = *(const float4*)(att + lane * 4);
    float m = -INFINITY, s = 0.f;
    float a0 = 0.f, a1 = 0.f, a2 = 0.f, a3 = 0.f;
    int beg = rp[n], end = rp[n + 1];
    int sidx = ss[beg];  // deg >= 1 (self-loop)
    f16x4 raw = *(const f16x4*)(xl + (size_t)sidx * HD + lane * 4);
    for (int i = beg; i < end; ++i) {
        float x0 = (float)raw[0], x1 = (float)raw[1], x2 = (float)raw[2], x3 = (float)raw[3];
        if (i + 1 < end) {
            int s2 = ss[i + 1];
            raw = *(const f16x4*)(xl + (size_t)s2 * HD + lane * 4);
        }
        float g0 = x0 + xr0, g1 = x1 + xr1, g2 = x2 + xr2, g3 = x3 + xr3;
        float l0 = g0 > 0.f ? g0 : NEG_SLOPE * g0;
        float l1 = g1 > 0.f ? g1 : NEG_SLOPE * g1;
        float l2 = g2 > 0.f ? g2 : NEG_SLOPE * g2;
        float l3 = g3 > 0.f ? g3 : NEG_SLOPE * g3;
        float p = attv.x * l0 + attv.y * l1 + attv.z * l2 + attv.w * l3;
        p += __shfl_xor(p, 1);
        p += __shfl_xor(p, 2);
        p += __shfl_xor(p, 4);  // e for head (lane>>3), replicated on its 8 lanes
        float mn = fmaxf(m, p);
        float cf = __expf(m - mn);
        float pe = __expf(p - mn);
        s = s * cf + pe;
        a0 = a0 * cf + pe * x0;
        a1 = a1 * cf + pe * x1;
        a2 = a2 * cf + pe * x2;
        a3 = a3 * cf + pe * x3;
        m = mn;
    }
    float inv = 1.f / (s + 1e-16f);
    float4 bv = *(const float4*)(bias + lane * 4);
    float o0 = a0 * inv + bv.x;
    float o1 = a1 * inv + bv.y;
    float o2 = a2 * inv + bv.z;
    float o3 = a3 * inv + bv.w;
    if (apply_elu) {
        o0 = o0 > 0.f ? o0 : __expf(o0) - 1.f;
        o1 = o1 > 0.f ? o1 : __expf(o1) - 1.f;
        o2 = o2 > 0.f ? o2 : __expf(o2) - 1.f;
        o3 = o3 > 0.f ? o3 : __expf(o3) - 1.f;
    }
    f16x4 o = {(f16)o0, (f16)o1, (f16)o2, (f16)o3};
    *(f16x4*)(hout + (size_t)n * HD + lane * 4) = o;
}

// ---------------- edge kernel layer 4, H=1 D=16, fused log_softmax -> d_out ----------------

__global__ __launch_bounds__(256) void edge_h1_kernel(
    const float* __restrict__ xl, const float* __restrict__ xr,
    const int* __restrict__ rp, const int* __restrict__ ss,
    const float* __restrict__ att, const float* __restrict__ bias,
    float* __restrict__ out, int N) {
    int wave = threadIdx.x >> 6;
    int lane = threadIdx.x & 63;
    int n = blockIdx.x * 4 + wave;
    if (n >= N) return;
    int d = lane & 15;
    float xrv = xr[(size_t)n * 16 + d];
    float attv = att[d];
    float m = -INFINITY, s = 0.f, acc = 0.f;
    int beg = rp[n], end = rp[n + 1];
    for (int i = beg; i < end; ++i) {
        int sidx = ss[i];
        float xv = xl[(size_t)sidx * 16 + d];
        float g = xv + xrv;
        float l = g > 0.f ? g : NEG_SLOPE * g;
        float p = attv * l;
        p += __shfl_xor(p, 1);
        p += __shfl_xor(p, 2);
        p += __shfl_xor(p, 4);
        p += __shfl_xor(p, 8);
        float mn = fmaxf(m, p);
        float cf = __expf(m - mn);
        float pe = __expf(p - mn);
        s = s * cf + pe;
        acc = acc * cf + pe * xv;
        m = mn;
    }
    float v = acc / (s + 1e-16f) + bias[d];
    float mx = v;
    mx = fmaxf(mx, __shfl_xor(mx, 1));
    mx = fmaxf(mx, __shfl_xor(mx, 2));
    mx = fmaxf(mx, __shfl_xor(mx, 4));
    mx = fmaxf(mx, __shfl_xor(mx, 8));
    float ex = __expf(v - mx);
    float se = ex;
    se += __shfl_xor(se, 1);
    se += __shfl_xor(se, 2);
    se += __shfl_xor(se, 4);
    se += __shfl_xor(se, 8);
    float res = v - mx - __logf(se);
    if (lane < 16) out[(size_t)n * 16 + d] = res;
}

// ---------------- launch ----------------

extern "C" void kernel_launch(void* const* d_in, const int* in_sizes, int n_in,
                              void* d_out, int out_size, void* d_ws, size_t ws_size,
                              hipStream_t stream) {
    const float* x    = (const float*)d_in[0];
    const int*   ei   = (const int*)d_in[1];
    const float* Wl1  = (const float*)d_in[2];
    const float* Wr1  = (const float*)d_in[3];
    const float* att1 = (const float*)d_in[4];
    const float* b1   = (const float*)d_in[5];
    const float* Wl2  = (const float*)d_in[6];
    const float* Wr2  = (const float*)d_in[7];
    const float* att2 = (const float*)d_in[8];
    const float* b2   = (const float*)d_in[9];
    const float* Wl3  = (const float*)d_in[10];
    const float* Wr3  = (const float*)d_in[11];
    const float* att3 = (const float*)d_in[12];
    const float* b3   = (const float*)d_in[13];
    const float* Wl4  = (const float*)d_in[14];
    const float* Wr4  = (const float*)d_in[15];
    const float* att4 = (const float*)d_in[16];
    const float* b4   = (const float*)d_in[17];

    const int N = in_sizes[0] / 128;
    const int E = in_sizes[1] / 2;
    const int* src = ei;
    const int* dst = ei + E;
    const int Etot = E + N;

    char* wsb = (char*)d_ws;
    size_t off = 0;
    auto alloc = [&](size_t bytes) -> void* {
        void* p = wsb + off;
        off += (bytes + 255) & ~(size_t)255;
        return p;
    };
    f16*   x16  = (f16*)alloc((size_t)N * 128 * 2);
    f16*   xl16 = (f16*)alloc((size_t)N * 256 * 2);
    f16*   xr16 = (f16*)alloc((size_t)N * 256 * 2);
    f16*   h16  = (f16*)alloc((size_t)N * 256 * 2);
    float* xl4  = (float*)alloc((size_t)N * 16 * 4);
    float* xr4  = (float*)alloc((size_t)N * 16 * 4);
    f16*   Wt1l = (f16*)alloc((size_t)256 * 128 * 2);
    f16*   Wt1r = (f16*)alloc((size_t)256 * 128 * 2);
    f16*   Wt2l = (f16*)alloc((size_t)256 * 256 * 2);
    f16*   Wt2r = (f16*)alloc((size_t)256 * 256 * 2);
    f16*   Wt3l = (f16*)alloc((size_t)256 * 256 * 2);
    f16*   Wt3r = (f16*)alloc((size_t)256 * 256 * 2);
    int*   cnt  = (int*)alloc((size_t)N * 4);
    int*   wof  = (int*)alloc((size_t)N * 4);
    int*   rp   = (int*)alloc((size_t)(N + 1) * 4);
    int*   ss   = (int*)alloc((size_t)Etot * 4);

    // conversions
    conv_f32_f16_kernel<<<idiv(N * 128, 1024), 256, 0, stream>>>(x, x16, N * 128);
    convT_kernel<<<dim3(4, 8), 256, 0, stream>>>(Wl1, Wt1l, 128);
    convT_kernel<<<dim3(4, 8), 256, 0, stream>>>(Wr1, Wt1r, 128);
    convT_kernel<<<dim3(8, 8), 256, 0, stream>>>(Wl2, Wt2l, 256);
    convT_kernel<<<dim3(8, 8), 256, 0, stream>>>(Wr2, Wt2r, 256);
    convT_kernel<<<dim3(8, 8), 256, 0, stream>>>(Wl3, Wt3l, 256);
    convT_kernel<<<dim3(8, 8), 256, 0, stream>>>(Wr3, Wt3r, 256);

    // CSR build
    zero_int_kernel<<<idiv(N, 256), 256, 0, stream>>>(cnt, N);
    hist_kernel<<<idiv(Etot, 256), 256, 0, stream>>>(dst, E, N, cnt);
    scan_kernel<<<1, 256, 0, stream>>>(cnt, rp, wof, N);
    scatter_kernel<<<idiv(Etot, 256), 256, 0, stream>>>(src, dst, E, N, wof, ss);

    dim3 gg(idiv(N, 128), 4);
    // layer 1 (K=128)
    gemm16_dual<<<gg, 256, 0, stream>>>(x16, N, 128, Wt1l, Wt1r, xl16, xr16);
    edge_h8_f16<<<idiv(N, 4), 256, 0, stream>>>(xl16, xr16, rp, ss, att1, b1, h16, N, 1);
    // layer 2
    gemm16_dual<<<gg, 256, 0, stream>>>(h16, N, 256, Wt2l, Wt2r, xl16, xr16);
    edge_h8_f16<<<idiv(N, 4), 256, 0, stream>>>(xl16, xr16, rp, ss, att2, b2, h16, N, 1);
    // layer 3
    gemm16_dual<<<gg, 256, 0, stream>>>(h16, N, 256, Wt3l, Wt3r, xl16, xr16);
    edge_h8_f16<<<idiv(N, 4), 256, 0, stream>>>(xl16, xr16, rp, ss, att3, b3, h16, N, 1);
    // layer 4 (M=16) + fused log_softmax
    gemm_small16<<<dim3(idiv(N, 16), 2), 256, 0, stream>>>(h16, N, Wl4, Wr4, xl4, xr4);
    edge_h1_kernel<<<idiv(N, 4), 256, 0, stream>>>(xl4, xr4, rp, ss, att4, b4, (float*)d_out, N);
}

// Round 3
// 580.704 us; speedup vs baseline: 2.0430x; 1.2688x over previous
//
#include <hip/hip_runtime.h>
#include <math.h>

#define NEG_SLOPE 0.2f

typedef _Float16 f16;
typedef _Float16 f16x2 __attribute__((ext_vector_type(2)));
typedef _Float16 f16x4 __attribute__((ext_vector_type(4)));
typedef _Float16 f16x8 __attribute__((ext_vector_type(8)));
typedef float f32x4 __attribute__((ext_vector_type(4)));

static inline int idiv(int a, int b) { return (a + b - 1) / b; }

// Packed activation layout for GEMM-A/B (fragment-major, matches LDS image):
//   elem(row, k) at ((row>>7)*(K>>3) + (k>>3))*128*8 + (row&127)*8 + (k&7)
// Each BK=64 K-chunk of a 128-row tile is a contiguous 16KB slab.

// ---------------- conversions ----------------

// x [N][128] f32 -> packed f16 (K=128), zero-pad rows >= N
__global__ __launch_bounds__(256) void conv_x_packed(const float* __restrict__ x,
                                                     f16* __restrict__ pa, int N) {
    int R = blockIdx.x;
    #pragma unroll
    for (int u = 0; u < 8; ++u) {
        int c = threadIdx.x + u * 256;  // chunk in [0, 2048)
        int g = c >> 7, r = c & 127;
        int row = R * 128 + r;
        f16x8 v;
        if (row < N) {
            float4 a = *(const float4*)(x + (size_t)row * 128 + g * 8);
            float4 b = *(const float4*)(x + (size_t)row * 128 + g * 8 + 4);
            v = (f16x8){(f16)a.x, (f16)a.y, (f16)a.z, (f16)a.w,
                        (f16)b.x, (f16)b.y, (f16)b.z, (f16)b.w};
        } else {
            v = (f16x8){0, 0, 0, 0, 0, 0, 0, 0};
        }
        *(f16x8*)(pa + ((size_t)(R * 16 + g) * 128 + r) * 8) = v;
    }
}

// W [K][256] f32 -> packed-B f16 (col-tiles), all 6 weight matrices in one launch
__global__ __launch_bounds__(256) void convT_all(
    const float* __restrict__ W1l, const float* __restrict__ W1r,
    const float* __restrict__ W2l, const float* __restrict__ W2r,
    const float* __restrict__ W3l, const float* __restrict__ W3r,
    f16* __restrict__ P1l, f16* __restrict__ P1r,
    f16* __restrict__ P2l, f16* __restrict__ P2r,
    f16* __restrict__ P3l, f16* __restrict__ P3r) {
    __shared__ float tbl[32][33];
    const float* W;
    f16* P;
    int K;
    switch (blockIdx.z) {
        case 0: W = W1l; P = P1l; K = 128; break;
        case 1: W = W1r; P = P1r; K = 128; break;
        case 2: W = W2l; P = P2l; K = 256; break;
        case 3: W = W2r; P = P2r; K = 256; break;
        case 4: W = W3l; P = P3l; K = 256; break;
        default: W = W3r; P = P3r; K = 256; break;
    }
    int bk = blockIdx.x * 32, bc = blockIdx.y * 32;
    if (bk >= K) return;
    int tx = threadIdx.x & 31, ty = threadIdx.x >> 5;  // ty 0..7
    #pragma unroll
    for (int i = 0; i < 32; i += 8)
        tbl[ty + i][tx] = W[(size_t)(bk + ty + i) * 256 + bc + tx];
    __syncthreads();
    if (threadIdx.x < 128) {
        int cl = threadIdx.x & 31;
        int gl = threadIdx.x >> 5;  // 0..3
        int col = bc + cl;
        int g = (bk >> 3) + gl;
        f16x8 v;
        #pragma unroll
        for (int j = 0; j < 8; ++j) v[j] = (f16)tbl[gl * 8 + j][cl];
        *(f16x8*)(P + ((size_t)((col >> 7) * (K >> 3) + g) * 128 + (col & 127)) * 8) = v;
    }
}

// ---------------- CSR build ----------------

__global__ void hist_kernel(const int* __restrict__ dst, int E, int N, int* __restrict__ cnt) {
    int i = blockIdx.x * blockDim.x + threadIdx.x;
    if (i >= E + N) return;
    int d = (i < E) ? dst[i] : (i - E);
    atomicAdd(&cnt[d], 1);
}

__global__ void scan_kernel(const int* __restrict__ cnt, int* __restrict__ row_ptr,
                            int* __restrict__ wofs, int N) {
    __shared__ int wsum[4];
    __shared__ int carry_s;
    int tid = threadIdx.x, lane = tid & 63, wid = tid >> 6;
    if (tid == 0) { carry_s = 0; row_ptr[0] = 0; }
    __syncthreads();
    for (int base = 0; base < N; base += 1024) {
        int i0 = base + tid * 4;
        int v0 = (i0 + 0 < N) ? cnt[i0 + 0] : 0;
        int v1 = (i0 + 1 < N) ? cnt[i0 + 1] : 0;
        int v2 = (i0 + 2 < N) ? cnt[i0 + 2] : 0;
        int v3 = (i0 + 3 < N) ? cnt[i0 + 3] : 0;
        int tsum = v0 + v1 + v2 + v3;
        int incl = tsum;
        #pragma unroll
        for (int off = 1; off < 64; off <<= 1) {
            int t = __shfl_up(incl, off);
            if (lane >= off) incl += t;
        }
        if (lane == 63) wsum[wid] = incl;
        __syncthreads();
        int w0 = wsum[0], w1 = wsum[1], w2 = wsum[2], w3 = wsum[3];
        int wbase = (wid > 0 ? w0 : 0) + (wid > 1 ? w1 : 0) + (wid > 2 ? w2 : 0);
        int tot = w0 + w1 + w2 + w3;
        int carry = carry_s;
        int pre = carry + wbase + incl - tsum;
        int p1 = pre + v0, p2 = p1 + v1, p3 = p2 + v2, p4 = p3 + v3;
        if (i0 + 0 < N) { wofs[i0 + 0] = pre; row_ptr[i0 + 1] = p1; }
        if (i0 + 1 < N) { wofs[i0 + 1] = p1;  row_ptr[i0 + 2] = p2; }
        if (i0 + 2 < N) { wofs[i0 + 2] = p2;  row_ptr[i0 + 3] = p3; }
        if (i0 + 3 < N) { wofs[i0 + 3] = p3;  row_ptr[i0 + 4] = p4; }
        __syncthreads();
        if (tid == 0) carry_s = carry + tot;
        __syncthreads();
    }
}

__global__ void scatter_kernel(const int* __restrict__ src, const int* __restrict__ dst,
                               int E, int N, int* __restrict__ wofs, int* __restrict__ sorted_src) {
    int i = blockIdx.x * blockDim.x + threadIdx.x;
    if (i >= E + N) return;
    int d, s;
    if (i < E) { d = dst[i]; s = src[i]; } else { d = i - E; s = d; }
    int pos = atomicAdd(&wofs[d], 1);
    sorted_src[pos] = s;
}

// ---------------- MFMA GEMM on packed inputs ----------------
// C[N,256] = A @ W for both Wl,Wr. Tile 128x128, BK=64 double-buffered via
// global_load_lds (packed layout -> each chunk is a contiguous 16KB slab).
// grid = ntile*4; bijective XCD-chunk swizzle co-locates the 4 blocks sharing
// an A-panel on one XCD (A re-read from that XCD's L2).

__device__ __forceinline__ void gll16(const f16* g, f16* l) {
#if __has_builtin(__builtin_amdgcn_global_load_lds)
    __builtin_amdgcn_global_load_lds((const __attribute__((address_space(1))) void*)g,
                                     (__attribute__((address_space(3))) void*)l, 16, 0, 0);
#else
    *(f16x8*)l = *(const f16x8*)g;  // fallback (slower)
#endif
}

__global__ __launch_bounds__(256) void gemm16_packed(
    const f16* __restrict__ PA, int N, int K,
    const f16* __restrict__ PBl, const f16* __restrict__ PBr,
    f16* __restrict__ Cl, f16* __restrict__ Cr) {
    __shared__ f16 lds[2][2][8192];  // [buf][A/B][16KB] = 64KB
    const int nblk = gridDim.x;
    int bid = blockIdx.x;
    int xcd = bid & 7, jj = bid >> 3;
    int nper = nblk >> 3, rem = nblk & 7;
    int slot = (xcd < rem) ? xcd * (nper + 1) + jj
                           : rem * (nper + 1) + (xcd - rem) * nper + jj;
    int R = slot >> 2, by = slot & 3;
    const f16* __restrict__ PB = (by >> 1) ? PBr : PBl;
    f16* __restrict__ C = (by >> 1) ? Cr : Cl;
    const int cb = by & 1;
    const int row0 = R * 128;
    const int col0 = cb * 128;
    const f16* Abase = PA + (size_t)R * 128 * K;
    const f16* Bbase = PB + (size_t)cb * 128 * K;
    const int t = threadIdx.x;
    const int lane = t & 63, wid = t >> 6;
    const int wr = (wid >> 1) * 64, wc = (wid & 1) * 64;
    const int lg = lane >> 4, lr = lane & 15;

    f32x4 acc[4][4];
    #pragma unroll
    for (int m = 0; m < 4; ++m)
        #pragma unroll
        for (int n = 0; n < 4; ++n) acc[m][n] = (f32x4){0.f, 0.f, 0.f, 0.f};

    auto stage = [&](int buf, int k0) {
        const f16* As = Abase + (size_t)k0 * 128 + t * 8;
        const f16* Bs = Bbase + (size_t)k0 * 128 + t * 8;
        f16* Al = &lds[buf][0][t * 8];
        f16* Bl = &lds[buf][1][t * 8];
        #pragma unroll
        for (int u = 0; u < 4; ++u) gll16(As + u * 2048, Al + u * 2048);
        #pragma unroll
        for (int u = 0; u < 4; ++u) gll16(Bs + u * 2048, Bl + u * 2048);
    };

    const int nk = K >> 6;
    stage(0, 0);
    asm volatile("s_waitcnt vmcnt(0)" ::: "memory");
    __syncthreads();
    for (int c = 0; c < nk; ++c) {
        if (c + 1 < nk) stage((c + 1) & 1, (c + 1) * 64);
        f16x8* Asp = (f16x8*)lds[c & 1][0];
        f16x8* Bsp = (f16x8*)lds[c & 1][1];
        #pragma unroll
        for (int s = 0; s < 2; ++s) {
            f16x8 af[4], bf[4];
            #pragma unroll
            for (int m = 0; m < 4; ++m) af[m] = Asp[(s * 4 + lg) * 128 + wr + m * 16 + lr];
            #pragma unroll
            for (int n = 0; n < 4; ++n) bf[n] = Bsp[(s * 4 + lg) * 128 + wc + n * 16 + lr];
            #pragma unroll
            for (int m = 0; m < 4; ++m)
                #pragma unroll
                for (int n = 0; n < 4; ++n)
                    acc[m][n] = __builtin_amdgcn_mfma_f32_16x16x32_f16(af[m], bf[n], acc[m][n], 0, 0, 0);
        }
        asm volatile("s_waitcnt vmcnt(0)" ::: "memory");
        __syncthreads();
    }
    // epilogue: C/D layout col=lane&15, row=(lane>>4)*4+reg (verified)
    #pragma unroll
    for (int m = 0; m < 4; ++m) {
        int row_b = row0 + wr + m * 16 + lg * 4;
        #pragma unroll
        for (int reg = 0; reg < 4; ++reg) {
            int row = row_b + reg;
            if (row < N) {
                #pragma unroll
                for (int n = 0; n < 4; ++n)
                    C[(size_t)row * 256 + col0 + wc + n * 16 + lr] = (f16)acc[m][n][reg];
            }
        }
    }
}

// ---------------- small GEMM layer 4: C[N,16] = A_packed[N,256] @ W[256,16] ----------------

__global__ __launch_bounds__(256) void gemm_small16(
    const f16* __restrict__ A, int N,
    const float* __restrict__ Wl, const float* __restrict__ Wr,
    float* __restrict__ Cl, float* __restrict__ Cr) {
    const int K = 256, M = 16;
    __shared__ float As[16][260];
    __shared__ float Ws[256 * 16];
    const float* __restrict__ W = (blockIdx.y == 0) ? Wl : Wr;
    float* __restrict__ C = (blockIdx.y == 0) ? Cl : Cr;
    int row0 = blockIdx.x * 16;
    int tid = threadIdx.x;
    {
        #pragma unroll
        for (int u = 0; u < 4; ++u)
            *(float4*)&Ws[tid * 16 + u * 4] = *(const float4*)(W + tid * 16 + u * 4);
        int r = tid >> 4;
        int c = (tid & 15) * 16;
        int row = row0 + r;
        if (row < N) {
            int R = row >> 7, rr = row & 127;
            const f16* base = A + ((size_t)(R * 32 + (c >> 3)) * 128 + rr) * 8;
            f16x8 v0 = *(const f16x8*)base;
            f16x8 v1 = *(const f16x8*)(base + 1024);
            #pragma unroll
            for (int j = 0; j < 8; ++j) {
                As[r][c + j] = (float)v0[j];
                As[r][c + 8 + j] = (float)v1[j];
            }
        } else {
            #pragma unroll
            for (int j = 0; j < 16; ++j) As[r][c + j] = 0.f;
        }
    }
    __syncthreads();
    int r = tid >> 4;
    int col = tid & 15;
    float acc = 0.f;
    #pragma unroll 8
    for (int k = 0; k < K; ++k) acc = fmaf(As[r][k], Ws[k * M + col], acc);
    int row = row0 + r;
    if (row < N) C[(size_t)row * M + col] = acc;
}

// ---------------- edge kernel, H=8 D=32 (HD=256): one wave per dst node ----------------
// packed f16 math + fdot2 scores + defer-max online softmax; writes h packed.

__global__ __launch_bounds__(256) void edge_h8_f16(
    const f16* __restrict__ xl, const f16* __restrict__ xr,
    const int* __restrict__ rp, const int* __restrict__ ss,
    const float* __restrict__ att, const float* __restrict__ bias,
    f16* __restrict__ hout, int N) {
    int wave = threadIdx.x >> 6;
    int lane = threadIdx.x & 63;
    int n = blockIdx.x * 4 + wave;
    if (n >= N) return;
    const int HD = 256;
    f16x4 xrr = *(const f16x4*)(xr + (size_t)n * HD + lane * 4);
    float4 attf = *(const float4*)(att + lane * 4);
    f16x2 at01 = {(f16)attf.x, (f16)attf.y};
    f16x2 at23 = {(f16)attf.z, (f16)attf.w};
    const f16 ns = (f16)NEG_SLOPE;
    float m = -INFINITY, s = 0.f;
    float a0 = 0.f, a1 = 0.f, a2 = 0.f, a3 = 0.f;
    int beg = rp[n], end = rp[n + 1];
    int last = end - 1;
    // depth-2 data prefetch, depth-3 index prefetch (branchless via clamp)
    int j1 = ss[beg];
    f16x4 r0 = *(const f16x4*)(xl + (size_t)j1 * HD + lane * 4);
    int j2 = ss[min(beg + 1, last)];
    f16x4 r1 = *(const f16x4*)(xl + (size_t)j2 * HD + lane * 4);
    int j3 = ss[min(beg + 2, last)];
    for (int i = beg; i < end; ++i) {
        f16x4 cur = r0;
        r0 = r1;
        r1 = *(const f16x4*)(xl + (size_t)j3 * HD + lane * 4);
        j3 = ss[min(i + 3, last)];
        f16x4 g = cur + xrr;                                  // v_pk_add_f16
        f16x4 gs = g * ns;                                    // v_pk_mul_f16
        f16x4 lk = __builtin_elementwise_max(g, gs);          // v_pk_max_f16
#if __has_builtin(__builtin_amdgcn_fdot2)
        f16x2 l01 = __builtin_shufflevector(lk, lk, 0, 1);
        f16x2 l23 = __builtin_shufflevector(lk, lk, 2, 3);
        float p = __builtin_amdgcn_fdot2(
            l23, at23, __builtin_amdgcn_fdot2(l01, at01, 0.f, false), false);
#else
        float p = (float)lk[0] * attf.x + (float)lk[1] * attf.y +
                  (float)lk[2] * attf.z + (float)lk[3] * attf.w;
#endif
        p += __shfl_xor(p, 1);
        p += __shfl_xor(p, 2);
        p += __shfl_xor(p, 4);  // e for head (lane>>3), replicated on its 8 lanes
        float d = p - m;        // first edge: +inf -> triggers rescale path
        if (__any(d > 8.f)) {
            float mn = fmaxf(m, p);
            float cf = __expf(m - mn);  // exp(-inf)=0 handles init
            s *= cf; a0 *= cf; a1 *= cf; a2 *= cf; a3 *= cf;
            m = mn;
            d = p - m;
        }
        float pe = __expf(d);
        s += pe;
        a0 = fmaf(pe, (float)cur[0], a0);
        a1 = fmaf(pe, (float)cur[1], a1);
        a2 = fmaf(pe, (float)cur[2], a2);
        a3 = fmaf(pe, (float)cur[3], a3);
    }
    float inv = 1.f / (s + 1e-16f);
    float4 bv = *(const float4*)(bias + lane * 4);
    float o0 = a0 * inv + bv.x;
    float o1 = a1 * inv + bv.y;
    float o2 = a2 * inv + bv.z;
    float o3 = a3 * inv + bv.w;
    o0 = o0 > 0.f ? o0 : __expf(o0) - 1.f;  // elu
    o1 = o1 > 0.f ? o1 : __expf(o1) - 1.f;
    o2 = o2 > 0.f ? o2 : __expf(o2) - 1.f;
    o3 = o3 > 0.f ? o3 : __expf(o3) - 1.f;
    // packed write (K=256): chunk g=lane>>1, j=(lane&1)*4
    int R = n >> 7, r = n & 127;
    f16* outp = hout + ((size_t)(R * 32 + (lane >> 1)) * 128 + r) * 8 + (lane & 1) * 4;
    f16x4 o = {(f16)o0, (f16)o1, (f16)o2, (f16)o3};
    *(f16x4*)outp = o;
}

// ---------------- edge kernel layer 4, H=1 D=16, fused log_softmax -> d_out ----------------

__global__ __launch_bounds__(256) void edge_h1_kernel(
    const float* __restrict__ xl, const float* __restrict__ xr,
    const int* __restrict__ rp, const int* __restrict__ ss,
    const float* __restrict__ att, const float* __restrict__ bias,
    float* __restrict__ out, int N) {
    int wave = threadIdx.x >> 6;
    int lane = threadIdx.x & 63;
    int n = blockIdx.x * 4 + wave;
    if (n >= N) return;
    int d = lane & 15;
    float xrv = xr[(size_t)n * 16 + d];
    float attv = att[d];
    float m = -INFINITY, s = 0.f, acc = 0.f;
    int beg = rp[n], end = rp[n + 1];
    for (int i = beg; i < end; ++i) {
        int sidx = ss[i];
        float xv = xl[(size_t)sidx * 16 + d];
        float g = xv + xrv;
        float l = fmaxf(g, NEG_SLOPE * g);
        float p = attv * l;
        p += __shfl_xor(p, 1);
        p += __shfl_xor(p, 2);
        p += __shfl_xor(p, 4);
        p += __shfl_xor(p, 8);
        float dd = p - m;
        if (__any(dd > 8.f)) {
            float mn = fmaxf(m, p);
            float cf = __expf(m - mn);
            s *= cf; acc *= cf;
            m = mn;
            dd = p - m;
        }
        float pe = __expf(dd);
        s += pe;
        acc = fmaf(pe, xv, acc);
    }
    float v = acc / (s + 1e-16f) + bias[d];
    float mx = v;
    mx = fmaxf(mx, __shfl_xor(mx, 1));
    mx = fmaxf(mx, __shfl_xor(mx, 2));
    mx = fmaxf(mx, __shfl_xor(mx, 4));
    mx = fmaxf(mx, __shfl_xor(mx, 8));
    float ex = __expf(v - mx);
    float se = ex;
    se += __shfl_xor(se, 1);
    se += __shfl_xor(se, 2);
    se += __shfl_xor(se, 4);
    se += __shfl_xor(se, 8);
    float res = v - mx - __logf(se);
    if (lane < 16) out[(size_t)n * 16 + d] = res;
}

// ---------------- launch ----------------

extern "C" void kernel_launch(void* const* d_in, const int* in_sizes, int n_in,
                              void* d_out, int out_size, void* d_ws, size_t ws_size,
                              hipStream_t stream) {
    const float* x    = (const float*)d_in[0];
    const int*   ei   = (const int*)d_in[1];
    const float* Wl1  = (const float*)d_in[2];
    const float* Wr1  = (const float*)d_in[3];
    const float* att1 = (const float*)d_in[4];
    const float* b1   = (const float*)d_in[5];
    const float* Wl2  = (const float*)d_in[6];
    const float* Wr2  = (const float*)d_in[7];
    const float* att2 = (const float*)d_in[8];
    const float* b2   = (const float*)d_in[9];
    const float* Wl3  = (const float*)d_in[10];
    const float* Wr3  = (const float*)d_in[11];
    const float* att3 = (const float*)d_in[12];
    const float* b3   = (const float*)d_in[13];
    const float* Wl4  = (const float*)d_in[14];
    const float* Wr4  = (const float*)d_in[15];
    const float* att4 = (const float*)d_in[16];
    const float* b4   = (const float*)d_in[17];

    const int N = in_sizes[0] / 128;
    const int E = in_sizes[1] / 2;
    const int* src = ei;
    const int* dst = ei + E;
    const int Etot = E + N;
    const int ntile = idiv(N, 128);  // 391

    char* wsb = (char*)d_ws;
    size_t off = 0;
    auto alloc = [&](size_t bytes) -> void* {
        void* p = wsb + off;
        off += (bytes + 255) & ~(size_t)255;
        return p;
    };
    f16*   PX   = (f16*)alloc((size_t)ntile * 128 * 128 * 2);  // packed x (K=128)
    f16*   PH   = (f16*)alloc((size_t)ntile * 128 * 256 * 2);  // packed h (K=256)
    f16*   xl16 = (f16*)alloc((size_t)N * 256 * 2);            // row-major
    f16*   xr16 = (f16*)alloc((size_t)N * 256 * 2);
    float* xl4  = (float*)alloc((size_t)N * 16 * 4);
    float* xr4  = (float*)alloc((size_t)N * 16 * 4);
    f16*   PB1l = (f16*)alloc((size_t)256 * 128 * 2);
    f16*   PB1r = (f16*)alloc((size_t)256 * 128 * 2);
    f16*   PB2l = (f16*)alloc((size_t)256 * 256 * 2);
    f16*   PB2r = (f16*)alloc((size_t)256 * 256 * 2);
    f16*   PB3l = (f16*)alloc((size_t)256 * 256 * 2);
    f16*   PB3r = (f16*)alloc((size_t)256 * 256 * 2);
    int*   cnt  = (int*)alloc((size_t)N * 4);
    int*   wof  = (int*)alloc((size_t)N * 4);
    int*   rp   = (int*)alloc((size_t)(N + 1) * 4);
    int*   ss   = (int*)alloc((size_t)Etot * 4);

    // conversions
    conv_x_packed<<<ntile, 256, 0, stream>>>(x, PX, N);
    convT_all<<<dim3(8, 8, 6), 256, 0, stream>>>(Wl1, Wr1, Wl2, Wr2, Wl3, Wr3,
                                                 PB1l, PB1r, PB2l, PB2r, PB3l, PB3r);

    // CSR build
    hipMemsetAsync(cnt, 0, (size_t)N * 4, stream);
    hist_kernel<<<idiv(Etot, 256), 256, 0, stream>>>(dst, E, N, cnt);
    scan_kernel<<<1, 256, 0, stream>>>(cnt, rp, wof, N);
    scatter_kernel<<<idiv(Etot, 256), 256, 0, stream>>>(src, dst, E, N, wof, ss);

    const int nblk = ntile * 4;
    // layer 1 (K=128)
    gemm16_packed<<<nblk, 256, 0, stream>>>(PX, N, 128, PB1l, PB1r, xl16, xr16);
    edge_h8_f16<<<idiv(N, 4), 256, 0, stream>>>(xl16, xr16, rp, ss, att1, b1, PH, N);
    // layer 2
    gemm16_packed<<<nblk, 256, 0, stream>>>(PH, N, 256, PB2l, PB2r, xl16, xr16);
    edge_h8_f16<<<idiv(N, 4), 256, 0, stream>>>(xl16, xr16, rp, ss, att2, b2, PH, N);
    // layer 3
    gemm16_packed<<<nblk, 256, 0, stream>>>(PH, N, 256, PB3l, PB3r, xl16, xr16);
    edge_h8_f16<<<idiv(N, 4), 256, 0, stream>>>(xl16, xr16, rp, ss, att3, b3, PH, N);
    // layer 4 (M=16) + fused log_softmax
    gemm_small16<<<dim3(idiv(N, 16), 2), 256, 0, stream>>>(PH, N, Wl4, Wr4, xl4, xr4);
    edge_h1_kernel<<<idiv(N, 4), 256, 0, stream>>>(xl4, xr4, rp, ss, att4, b4, (float*)d_out, N);
}

// Round 4
// 453.160 us; speedup vs baseline: 2.6181x; 1.2815x over previous
//
#include <hip/hip_runtime.h>
#include <math.h>

#define NEG_SLOPE 0.2f

typedef _Float16 f16;
typedef _Float16 f16x2 __attribute__((ext_vector_type(2)));
typedef _Float16 f16x4 __attribute__((ext_vector_type(4)));
typedef _Float16 f16x8 __attribute__((ext_vector_type(8)));
typedef float f32x4 __attribute__((ext_vector_type(4)));

static inline int idiv(int a, int b) { return (a + b - 1) / b; }

// Packed activation layout for GEMM-A/B (fragment-major, matches LDS image):
//   elem(row, k) at ((row>>7)*(K>>3) + (k>>3))*128*8 + (row&127)*8 + (k&7)
// Each BK=64 K-chunk of a 128-row tile is a contiguous 16KB slab.

// ---------------- conversions ----------------

__global__ __launch_bounds__(256) void conv_x_packed(const float* __restrict__ x,
                                                     f16* __restrict__ pa, int N) {
    int R = blockIdx.x;
    #pragma unroll
    for (int u = 0; u < 8; ++u) {
        int c = threadIdx.x + u * 256;  // chunk in [0, 2048)
        int g = c >> 7, r = c & 127;
        int row = R * 128 + r;
        f16x8 v;
        if (row < N) {
            float4 a = *(const float4*)(x + (size_t)row * 128 + g * 8);
            float4 b = *(const float4*)(x + (size_t)row * 128 + g * 8 + 4);
            v = (f16x8){(f16)a.x, (f16)a.y, (f16)a.z, (f16)a.w,
                        (f16)b.x, (f16)b.y, (f16)b.z, (f16)b.w};
        } else {
            v = (f16x8){0, 0, 0, 0, 0, 0, 0, 0};
        }
        *(f16x8*)(pa + ((size_t)(R * 16 + g) * 128 + r) * 8) = v;
    }
}

__global__ __launch_bounds__(256) void convT_all(
    const float* __restrict__ W1l, const float* __restrict__ W1r,
    const float* __restrict__ W2l, const float* __restrict__ W2r,
    const float* __restrict__ W3l, const float* __restrict__ W3r,
    f16* __restrict__ P1l, f16* __restrict__ P1r,
    f16* __restrict__ P2l, f16* __restrict__ P2r,
    f16* __restrict__ P3l, f16* __restrict__ P3r) {
    __shared__ float tbl[32][33];
    const float* W;
    f16* P;
    int K;
    switch (blockIdx.z) {
        case 0: W = W1l; P = P1l; K = 128; break;
        case 1: W = W1r; P = P1r; K = 128; break;
        case 2: W = W2l; P = P2l; K = 256; break;
        case 3: W = W2r; P = P2r; K = 256; break;
        case 4: W = W3l; P = P3l; K = 256; break;
        default: W = W3r; P = P3r; K = 256; break;
    }
    int bk = blockIdx.x * 32, bc = blockIdx.y * 32;
    if (bk >= K) return;
    int tx = threadIdx.x & 31, ty = threadIdx.x >> 5;
    #pragma unroll
    for (int i = 0; i < 32; i += 8)
        tbl[ty + i][tx] = W[(size_t)(bk + ty + i) * 256 + bc + tx];
    __syncthreads();
    if (threadIdx.x < 128) {
        int cl = threadIdx.x & 31;
        int gl = threadIdx.x >> 5;
        int col = bc + cl;
        int g = (bk >> 3) + gl;
        f16x8 v;
        #pragma unroll
        for (int j = 0; j < 8; ++j) v[j] = (f16)tbl[gl * 8 + j][cl];
        *(f16x8*)(P + ((size_t)((col >> 7) * (K >> 3) + g) * 128 + (col & 127)) * 8) = v;
    }
}

// ---------------- CSR build ----------------

__global__ void hist_kernel(const int* __restrict__ dst, int E, int N, int* __restrict__ cnt) {
    int i = blockIdx.x * blockDim.x + threadIdx.x;
    if (i >= E + N) return;
    int d = (i < E) ? dst[i] : (i - E);
    atomicAdd(&cnt[d], 1);
}

// 3-kernel scan: per-block sums -> scan partials -> local rescan+offset
__global__ __launch_bounds__(256) void scanA(const int* __restrict__ cnt,
                                             int* __restrict__ bsum, int N) {
    __shared__ int ws[4];
    int tid = threadIdx.x, lane = tid & 63, wid = tid >> 6;
    int i0 = blockIdx.x * 1024 + tid * 4;
    int s = 0;
    if (i0 + 3 < N) {
        int4 v = *(const int4*)(cnt + i0);
        s = v.x + v.y + v.z + v.w;
    } else {
        for (int j = 0; j < 4; ++j)
            if (i0 + j < N) s += cnt[i0 + j];
    }
    #pragma unroll
    for (int o = 1; o < 64; o <<= 1) s += __shfl_xor(s, o);
    if (lane == 0) ws[wid] = s;
    __syncthreads();
    if (tid == 0) bsum[blockIdx.x] = ws[0] + ws[1] + ws[2] + ws[3];
}

__global__ __launch_bounds__(256) void scanB(int* __restrict__ bsum, int nb) {
    __shared__ int ws[4];
    int tid = threadIdx.x, lane = tid & 63, wid = tid >> 6;
    int v = (tid < nb) ? bsum[tid] : 0;
    int incl = v;
    #pragma unroll
    for (int o = 1; o < 64; o <<= 1) {
        int t = __shfl_up(incl, o);
        if (lane >= o) incl += t;
    }
    if (lane == 63) ws[wid] = incl;
    __syncthreads();
    int add = 0;
    for (int w = 0; w < wid; ++w) add += ws[w];
    if (tid < nb) bsum[tid] = add + incl - v;  // exclusive
}

__global__ __launch_bounds__(256) void scanC(const int* __restrict__ cnt,
                                             const int* __restrict__ bsum,
                                             int* __restrict__ rp, int* __restrict__ wofs, int N) {
    __shared__ int ws[4];
    __shared__ int base_s;
    int tid = threadIdx.x, lane = tid & 63, wid = tid >> 6;
    int i0 = blockIdx.x * 1024 + tid * 4;
    int v0 = (i0 + 0 < N) ? cnt[i0 + 0] : 0;
    int v1 = (i0 + 1 < N) ? cnt[i0 + 1] : 0;
    int v2 = (i0 + 2 < N) ? cnt[i0 + 2] : 0;
    int v3 = (i0 + 3 < N) ? cnt[i0 + 3] : 0;
    int t4 = v0 + v1 + v2 + v3;
    int incl = t4;
    #pragma unroll
    for (int o = 1; o < 64; o <<= 1) {
        int t = __shfl_up(incl, o);
        if (lane >= o) incl += t;
    }
    if (lane == 63) ws[wid] = incl;
    if (tid == 0) base_s = bsum[blockIdx.x];
    __syncthreads();
    int wadd = 0;
    for (int w = 0; w < wid; ++w) wadd += ws[w];
    int pre = base_s + wadd + incl - t4;
    int p1 = pre + v0, p2 = p1 + v1, p3 = p2 + v2, p4 = p3 + v3;
    if (i0 + 0 < N) { wofs[i0 + 0] = pre; rp[i0 + 1] = p1; }
    if (i0 + 1 < N) { wofs[i0 + 1] = p1;  rp[i0 + 2] = p2; }
    if (i0 + 2 < N) { wofs[i0 + 2] = p2;  rp[i0 + 3] = p3; }
    if (i0 + 3 < N) { wofs[i0 + 3] = p3;  rp[i0 + 4] = p4; }
    if (blockIdx.x == 0 && tid == 0) rp[0] = 0;
}

__global__ void scatter_kernel(const int* __restrict__ src, const int* __restrict__ dst,
                               int E, int N, int* __restrict__ wofs, int* __restrict__ sorted_src) {
    int i = blockIdx.x * blockDim.x + threadIdx.x;
    if (i >= E + N) return;
    int d, s;
    if (i < E) { d = dst[i]; s = src[i]; } else { d = i - E; s = d; }
    int pos = atomicAdd(&wofs[d], 1);
    sorted_src[pos] = s;
}

// ---------------- MFMA GEMM on packed inputs ----------------

__device__ __forceinline__ void gll16(const f16* g, f16* l) {
#if __has_builtin(__builtin_amdgcn_global_load_lds)
    __builtin_amdgcn_global_load_lds((const __attribute__((address_space(1))) void*)g,
                                     (__attribute__((address_space(3))) void*)l, 16, 0, 0);
#else
    *(f16x8*)l = *(const f16x8*)g;
#endif
}

__global__ __launch_bounds__(256) void gemm16_packed(
    const f16* __restrict__ PA, int N, int K,
    const f16* __restrict__ PBl, const f16* __restrict__ PBr,
    f16* __restrict__ Cl, f16* __restrict__ Cr) {
    __shared__ f16 lds[2][2][8192];  // 64KB
    const int nblk = gridDim.x;
    int bid = blockIdx.x;
    int xcd = bid & 7, jj = bid >> 3;
    int nper = nblk >> 3, rem = nblk & 7;
    int slot = (xcd < rem) ? xcd * (nper + 1) + jj
                           : rem * (nper + 1) + (xcd - rem) * nper + jj;
    int R = slot >> 2, by = slot & 3;
    const f16* __restrict__ PB = (by >> 1) ? PBr : PBl;
    f16* __restrict__ C = (by >> 1) ? Cr : Cl;
    const int cb = by & 1;
    const int row0 = R * 128;
    const int col0 = cb * 128;
    const f16* Abase = PA + (size_t)R * 128 * K;
    const f16* Bbase = PB + (size_t)cb * 128 * K;
    const int t = threadIdx.x;
    const int lane = t & 63, wid = t >> 6;
    const int wr = (wid >> 1) * 64, wc = (wid & 1) * 64;
    const int lg = lane >> 4, lr = lane & 15;

    f32x4 acc[4][4];
    #pragma unroll
    for (int m = 0; m < 4; ++m)
        #pragma unroll
        for (int n = 0; n < 4; ++n) acc[m][n] = (f32x4){0.f, 0.f, 0.f, 0.f};

    auto stage = [&](int buf, int k0) {
        const f16* As = Abase + (size_t)k0 * 128 + t * 8;
        const f16* Bs = Bbase + (size_t)k0 * 128 + t * 8;
        f16* Al = &lds[buf][0][t * 8];
        f16* Bl = &lds[buf][1][t * 8];
        #pragma unroll
        for (int u = 0; u < 4; ++u) gll16(As + u * 2048, Al + u * 2048);
        #pragma unroll
        for (int u = 0; u < 4; ++u) gll16(Bs + u * 2048, Bl + u * 2048);
    };

    const int nk = K >> 6;
    stage(0, 0);
    asm volatile("s_waitcnt vmcnt(0)" ::: "memory");
    __syncthreads();
    for (int c = 0; c < nk; ++c) {
        if (c + 1 < nk) stage((c + 1) & 1, (c + 1) * 64);
        f16x8* Asp = (f16x8*)lds[c & 1][0];
        f16x8* Bsp = (f16x8*)lds[c & 1][1];
        #pragma unroll
        for (int s = 0; s < 2; ++s) {
            f16x8 af[4], bf[4];
            #pragma unroll
            for (int m = 0; m < 4; ++m) af[m] = Asp[(s * 4 + lg) * 128 + wr + m * 16 + lr];
            #pragma unroll
            for (int n = 0; n < 4; ++n) bf[n] = Bsp[(s * 4 + lg) * 128 + wc + n * 16 + lr];
            #pragma unroll
            for (int m = 0; m < 4; ++m)
                #pragma unroll
                for (int n = 0; n < 4; ++n)
                    acc[m][n] = __builtin_amdgcn_mfma_f32_16x16x32_f16(af[m], bf[n], acc[m][n], 0, 0, 0);
        }
        asm volatile("s_waitcnt vmcnt(0)" ::: "memory");
        __syncthreads();
    }
    #pragma unroll
    for (int m = 0; m < 4; ++m) {
        int row_b = row0 + wr + m * 16 + lg * 4;
        #pragma unroll
        for (int reg = 0; reg < 4; ++reg) {
            int row = row_b + reg;
            if (row < N) {
                #pragma unroll
                for (int n = 0; n < 4; ++n)
                    C[(size_t)row * 256 + col0 + wc + n * 16 + lr] = (f16)acc[m][n][reg];
            }
        }
    }
}

// ---------------- small GEMM layer 4 ----------------

__global__ __launch_bounds__(256) void gemm_small16(
    const f16* __restrict__ A, int N,
    const float* __restrict__ Wl, const float* __restrict__ Wr,
    float* __restrict__ Cl, float* __restrict__ Cr) {
    const int K = 256, M = 16;
    __shared__ float As[16][260];
    __shared__ float Ws[256 * 16];
    const float* __restrict__ W = (blockIdx.y == 0) ? Wl : Wr;
    float* __restrict__ C = (blockIdx.y == 0) ? Cl : Cr;
    int row0 = blockIdx.x * 16;
    int tid = threadIdx.x;
    {
        #pragma unroll
        for (int u = 0; u < 4; ++u)
            *(float4*)&Ws[tid * 16 + u * 4] = *(const float4*)(W + tid * 16 + u * 4);
        int r = tid >> 4;
        int c = (tid & 15) * 16;
        int row = row0 + r;
        if (row < N) {
            int R = row >> 7, rr = row & 127;
            const f16* base = A + ((size_t)(R * 32 + (c >> 3)) * 128 + rr) * 8;
            f16x8 v0 = *(const f16x8*)base;
            f16x8 v1 = *(const f16x8*)(base + 1024);
            #pragma unroll
            for (int j = 0; j < 8; ++j) {
                As[r][c + j] = (float)v0[j];
                As[r][c + 8 + j] = (float)v1[j];
            }
        } else {
            #pragma unroll
            for (int j = 0; j < 16; ++j) As[r][c + j] = 0.f;
        }
    }
    __syncthreads();
    int r = tid >> 4;
    int col = tid & 15;
    float acc = 0.f;
    #pragma unroll 8
    for (int k = 0; k < K; ++k) acc = fmaf(As[r][k], Ws[k * M + col], acc);
    int row = row0 + r;
    if (row < N) C[(size_t)row * M + col] = acc;
}

// ---------------- edge kernel, H=8 D=32: TWO nodes per wave (32 lanes each) ----------------
// 8 dims/lane (f16x8 = 16B gather), depth-3 data / depth-4 index prefetch,
// defer-max online softmax; writes h packed (one contiguous f16x8 store/lane).

__global__ __launch_bounds__(256) void edge_h8_f16(
    const f16* __restrict__ xl, const f16* __restrict__ xr,
    const int* __restrict__ rp, const int* __restrict__ ss,
    const float* __restrict__ att, const float* __restrict__ bias,
    f16* __restrict__ hout, int N) {
    int tid = threadIdx.x;
    int half = tid >> 5;   // 0..7 within block
    int hl = tid & 31;     // lane within half; dims hl*8..hl*8+7
    int n = blockIdx.x * 8 + half;
    if (n >= N) return;
    const int HD = 256;
    f16x8 xrr = *(const f16x8*)(xr + (size_t)n * HD + hl * 8);
    float4 atlo = *(const float4*)(att + hl * 8);
    float4 athi = *(const float4*)(att + hl * 8 + 4);
    f16x2 at01 = {(f16)atlo.x, (f16)atlo.y};
    f16x2 at23 = {(f16)atlo.z, (f16)atlo.w};
    f16x2 at45 = {(f16)athi.x, (f16)athi.y};
    f16x2 at67 = {(f16)athi.z, (f16)athi.w};
    const f16 ns = (f16)NEG_SLOPE;
    float m = -INFINITY, s = 0.f;
    float a[8];
    #pragma unroll
    for (int j = 0; j < 8; ++j) a[j] = 0.f;
    int beg = rp[n], end = rp[n + 1];
    int last = end - 1;
    f16x8 r0 = *(const f16x8*)(xl + (size_t)ss[beg] * HD + hl * 8);
    f16x8 r1 = *(const f16x8*)(xl + (size_t)ss[min(beg + 1, last)] * HD + hl * 8);
    f16x8 r2 = *(const f16x8*)(xl + (size_t)ss[min(beg + 2, last)] * HD + hl * 8);
    int j3 = ss[min(beg + 3, last)];
    for (int i = beg; i < end; ++i) {
        f16x8 cur = r0;
        r0 = r1;
        r1 = r2;
        r2 = *(const f16x8*)(xl + (size_t)j3 * HD + hl * 8);
        j3 = ss[min(i + 4, last)];
        f16x8 g = cur + xrr;
        f16x8 gs = g * ns;
        f16x8 lk = __builtin_elementwise_max(g, gs);
#if __has_builtin(__builtin_amdgcn_fdot2)
        f16x2 l01 = __builtin_shufflevector(lk, lk, 0, 1);
        f16x2 l23 = __builtin_shufflevector(lk, lk, 2, 3);
        f16x2 l45 = __builtin_shufflevector(lk, lk, 4, 5);
        f16x2 l67 = __builtin_shufflevector(lk, lk, 6, 7);
        float p = __builtin_amdgcn_fdot2(l01, at01, 0.f, false);
        p = __builtin_amdgcn_fdot2(l23, at23, p, false);
        p = __builtin_amdgcn_fdot2(l45, at45, p, false);
        p = __builtin_amdgcn_fdot2(l67, at67, p, false);
#else
        float p = 0.f;
        p += (float)lk[0] * atlo.x + (float)lk[1] * atlo.y +
             (float)lk[2] * atlo.z + (float)lk[3] * atlo.w +
             (float)lk[4] * athi.x + (float)lk[5] * athi.y +
             (float)lk[6] * athi.z + (float)lk[7] * athi.w;
#endif
        p += __shfl_xor(p, 1);
        p += __shfl_xor(p, 2);  // head = 4 lanes (32 dims), e replicated on them
        float d = p - m;        // first edge: +inf -> rescale path
        if (__any(d > 8.f)) {
            float mn = fmaxf(m, p);
            float cf = __expf(m - mn);
            s *= cf;
            #pragma unroll
            for (int j = 0; j < 8; ++j) a[j] *= cf;
            m = mn;
            d = p - m;
        }
        float pe = __expf(d);
        s += pe;
        #pragma unroll
        for (int j = 0; j < 8; ++j) a[j] = fmaf(pe, (float)cur[j], a[j]);
    }
    float inv = 1.f / (s + 1e-16f);
    float4 blo = *(const float4*)(bias + hl * 8);
    float4 bhi = *(const float4*)(bias + hl * 8 + 4);
    float o[8];
    o[0] = a[0] * inv + blo.x; o[1] = a[1] * inv + blo.y;
    o[2] = a[2] * inv + blo.z; o[3] = a[3] * inv + blo.w;
    o[4] = a[4] * inv + bhi.x; o[5] = a[5] * inv + bhi.y;
    o[6] = a[6] * inv + bhi.z; o[7] = a[7] * inv + bhi.w;
    f16x8 ov;
    #pragma unroll
    for (int j = 0; j < 8; ++j) {
        float e = o[j] > 0.f ? o[j] : __expf(o[j]) - 1.f;  // elu
        ov[j] = (f16)e;
    }
    // packed write (K=256): lane hl owns chunk g=hl entirely -> contiguous f16x8
    *(f16x8*)(hout + ((size_t)((n >> 7) * 32 + hl) * 128 + (n & 127)) * 8) = ov;
}

// ---------------- edge kernel layer 4: FOUR nodes per wave (16 lanes each) ----------------

__global__ __launch_bounds__(256) void edge_h1_kernel(
    const float* __restrict__ xl, const float* __restrict__ xr,
    const int* __restrict__ rp, const int* __restrict__ ss,
    const float* __restrict__ att, const float* __restrict__ bias,
    float* __restrict__ out, int N) {
    int tid = threadIdx.x;
    int grp = tid >> 4;  // 0..15 within block
    int gl = tid & 15;   // dim
    int n = blockIdx.x * 16 + grp;
    if (n >= N) return;
    float xrv = xr[(size_t)n * 16 + gl];
    float attv = att[gl];
    float bv = bias[gl];
    float m = -INFINITY, s = 0.f, acc = 0.f;
    int beg = rp[n], end = rp[n + 1], last = end - 1;
    float x0 = xl[(size_t)ss[beg] * 16 + gl];
    float x1 = xl[(size_t)ss[min(beg + 1, last)] * 16 + gl];
    int j3 = ss[min(beg + 2, last)];
    for (int i = beg; i < end; ++i) {
        float xv = x0;
        x0 = x1;
        x1 = xl[(size_t)j3 * 16 + gl];
        j3 = ss[min(i + 3, last)];
        float g = xv + xrv;
        float l = fmaxf(g, NEG_SLOPE * g);
        float p = attv * l;
        p += __shfl_xor(p, 1);
        p += __shfl_xor(p, 2);
        p += __shfl_xor(p, 4);
        p += __shfl_xor(p, 8);
        float dd = p - m;
        if (__any(dd > 8.f)) {
            float mn = fmaxf(m, p);
            float cf = __expf(m - mn);
            s *= cf;
            acc *= cf;
            m = mn;
            dd = p - m;
        }
        float pe = __expf(dd);
        s += pe;
        acc = fmaf(pe, xv, acc);
    }
    float v = acc / (s + 1e-16f) + bv;
    float mx = v;
    mx = fmaxf(mx, __shfl_xor(mx, 1));
    mx = fmaxf(mx, __shfl_xor(mx, 2));
    mx = fmaxf(mx, __shfl_xor(mx, 4));
    mx = fmaxf(mx, __shfl_xor(mx, 8));
    float ex = __expf(v - mx);
    float se = ex;
    se += __shfl_xor(se, 1);
    se += __shfl_xor(se, 2);
    se += __shfl_xor(se, 4);
    se += __shfl_xor(se, 8);
    out[(size_t)n * 16 + gl] = v - mx - __logf(se);
}

// ---------------- launch ----------------

extern "C" void kernel_launch(void* const* d_in, const int* in_sizes, int n_in,
                              void* d_out, int out_size, void* d_ws, size_t ws_size,
                              hipStream_t stream) {
    const float* x    = (const float*)d_in[0];
    const int*   ei   = (const int*)d_in[1];
    const float* Wl1  = (const float*)d_in[2];
    const float* Wr1  = (const float*)d_in[3];
    const float* att1 = (const float*)d_in[4];
    const float* b1   = (const float*)d_in[5];
    const float* Wl2  = (const float*)d_in[6];
    const float* Wr2  = (const float*)d_in[7];
    const float* att2 = (const float*)d_in[8];
    const float* b2   = (const float*)d_in[9];
    const float* Wl3  = (const float*)d_in[10];
    const float* Wr3  = (const float*)d_in[11];
    const float* att3 = (const float*)d_in[12];
    const float* b3   = (const float*)d_in[13];
    const float* Wl4  = (const float*)d_in[14];
    const float* Wr4  = (const float*)d_in[15];
    const float* att4 = (const float*)d_in[16];
    const float* b4   = (const float*)d_in[17];

    const int N = in_sizes[0] / 128;
    const int E = in_sizes[1] / 2;
    const int* src = ei;
    const int* dst = ei + E;
    const int Etot = E + N;
    const int ntile = idiv(N, 128);

    char* wsb = (char*)d_ws;
    size_t off = 0;
    auto alloc = [&](size_t bytes) -> void* {
        void* p = wsb + off;
        off += (bytes + 255) & ~(size_t)255;
        return p;
    };
    f16*   PX   = (f16*)alloc((size_t)ntile * 128 * 128 * 2);
    f16*   PH   = (f16*)alloc((size_t)ntile * 128 * 256 * 2);
    f16*   xl16 = (f16*)alloc((size_t)N * 256 * 2);
    f16*   xr16 = (f16*)alloc((size_t)N * 256 * 2);
    float* xl4  = (float*)alloc((size_t)N * 16 * 4);
    float* xr4  = (float*)alloc((size_t)N * 16 * 4);
    f16*   PB1l = (f16*)alloc((size_t)256 * 128 * 2);
    f16*   PB1r = (f16*)alloc((size_t)256 * 128 * 2);
    f16*   PB2l = (f16*)alloc((size_t)256 * 256 * 2);
    f16*   PB2r = (f16*)alloc((size_t)256 * 256 * 2);
    f16*   PB3l = (f16*)alloc((size_t)256 * 256 * 2);
    f16*   PB3r = (f16*)alloc((size_t)256 * 256 * 2);
    int*   cnt  = (int*)alloc((size_t)N * 4);
    int*   wof  = (int*)alloc((size_t)N * 4);
    int*   rp   = (int*)alloc((size_t)(N + 1) * 4);
    int*   ss   = (int*)alloc((size_t)Etot * 4);
    int*   bsum = (int*)alloc((size_t)idiv(N, 1024) * 4);

    // conversions
    conv_x_packed<<<ntile, 256, 0, stream>>>(x, PX, N);
    convT_all<<<dim3(8, 8, 6), 256, 0, stream>>>(Wl1, Wr1, Wl2, Wr2, Wl3, Wr3,
                                                 PB1l, PB1r, PB2l, PB2r, PB3l, PB3r);

    // CSR build
    hipMemsetAsync(cnt, 0, (size_t)N * 4, stream);
    hist_kernel<<<idiv(Etot, 256), 256, 0, stream>>>(dst, E, N, cnt);
    const int nb = idiv(N, 1024);
    scanA<<<nb, 256, 0, stream>>>(cnt, bsum, N);
    scanB<<<1, 256, 0, stream>>>(bsum, nb);
    scanC<<<nb, 256, 0, stream>>>(cnt, bsum, rp, wof, N);
    scatter_kernel<<<idiv(Etot, 256), 256, 0, stream>>>(src, dst, E, N, wof, ss);

    const int nblk = ntile * 4;
    // layer 1 (K=128)
    gemm16_packed<<<nblk, 256, 0, stream>>>(PX, N, 128, PB1l, PB1r, xl16, xr16);
    edge_h8_f16<<<idiv(N, 8), 256, 0, stream>>>(xl16, xr16, rp, ss, att1, b1, PH, N);
    // layer 2
    gemm16_packed<<<nblk, 256, 0, stream>>>(PH, N, 256, PB2l, PB2r, xl16, xr16);
    edge_h8_f16<<<idiv(N, 8), 256, 0, stream>>>(xl16, xr16, rp, ss, att2, b2, PH, N);
    // layer 3
    gemm16_packed<<<nblk, 256, 0, stream>>>(PH, N, 256, PB3l, PB3r, xl16, xr16);
    edge_h8_f16<<<idiv(N, 8), 256, 0, stream>>>(xl16, xr16, rp, ss, att3, b3, PH, N);
    // layer 4 (M=16) + fused log_softmax
    gemm_small16<<<dim3(idiv(N, 16), 2), 256, 0, stream>>>(PH, N, Wl4, Wr4, xl4, xr4);
    edge_h1_kernel<<<idiv(N, 16), 256, 0, stream>>>(xl4, xr4, rp, ss, att4, b4, (float*)d_out, N);
}

// Round 5
// 444.163 us; speedup vs baseline: 2.6711x; 1.0203x over previous
//
#include <hip/hip_runtime.h>
#include <math.h>

#define NEG_SLOPE 0.2f

typedef _Float16 f16;
typedef _Float16 f16x2 __attribute__((ext_vector_type(2)));
typedef _Float16 f16x4 __attribute__((ext_vector_type(4)));
typedef _Float16 f16x8 __attribute__((ext_vector_type(8)));
typedef float f32x4 __attribute__((ext_vector_type(4)));

static inline int idiv(int a, int b) { return (a + b - 1) / b; }

// Packed activation layout for GEMM-A/B (fragment-major, matches LDS image):
//   elem(row, k) at ((row>>7)*(K>>3) + (k>>3))*128*8 + (row&127)*8 + (k&7)

// ---------------- conversions ----------------

__global__ __launch_bounds__(256) void conv_x_packed(const float* __restrict__ x,
                                                     f16* __restrict__ pa, int N) {
    int R = blockIdx.x;
    #pragma unroll
    for (int u = 0; u < 8; ++u) {
        int c = threadIdx.x + u * 256;
        int g = c >> 7, r = c & 127;
        int row = R * 128 + r;
        f16x8 v;
        if (row < N) {
            float4 a = *(const float4*)(x + (size_t)row * 128 + g * 8);
            float4 b = *(const float4*)(x + (size_t)row * 128 + g * 8 + 4);
            v = (f16x8){(f16)a.x, (f16)a.y, (f16)a.z, (f16)a.w,
                        (f16)b.x, (f16)b.y, (f16)b.z, (f16)b.w};
        } else {
            v = (f16x8){0, 0, 0, 0, 0, 0, 0, 0};
        }
        *(f16x8*)(pa + ((size_t)(R * 16 + g) * 128 + r) * 8) = v;
    }
}

__global__ __launch_bounds__(256) void convT_all(
    const float* __restrict__ W1l, const float* __restrict__ W1r,
    const float* __restrict__ W2l, const float* __restrict__ W2r,
    const float* __restrict__ W3l, const float* __restrict__ W3r,
    f16* __restrict__ P1l, f16* __restrict__ P1r,
    f16* __restrict__ P2l, f16* __restrict__ P2r,
    f16* __restrict__ P3l, f16* __restrict__ P3r) {
    __shared__ float tbl[32][33];
    const float* W;
    f16* P;
    int K;
    switch (blockIdx.z) {
        case 0: W = W1l; P = P1l; K = 128; break;
        case 1: W = W1r; P = P1r; K = 128; break;
        case 2: W = W2l; P = P2l; K = 256; break;
        case 3: W = W2r; P = P2r; K = 256; break;
        case 4: W = W3l; P = P3l; K = 256; break;
        default: W = W3r; P = P3r; K = 256; break;
    }
    int bk = blockIdx.x * 32, bc = blockIdx.y * 32;
    if (bk >= K) return;
    int tx = threadIdx.x & 31, ty = threadIdx.x >> 5;
    #pragma unroll
    for (int i = 0; i < 32; i += 8)
        tbl[ty + i][tx] = W[(size_t)(bk + ty + i) * 256 + bc + tx];
    __syncthreads();
    if (threadIdx.x < 128) {
        int cl = threadIdx.x & 31;
        int gl = threadIdx.x >> 5;
        int col = bc + cl;
        int g = (bk >> 3) + gl;
        f16x8 v;
        #pragma unroll
        for (int j = 0; j < 8; ++j) v[j] = (f16)tbl[gl * 8 + j][cl];
        *(f16x8*)(P + ((size_t)((col >> 7) * (K >> 3) + g) * 128 + (col & 127)) * 8) = v;
    }
}

// ---------------- CSR build ----------------

__global__ void hist_kernel(const int* __restrict__ dst, int E, int N, int* __restrict__ cnt) {
    int i = blockIdx.x * blockDim.x + threadIdx.x;
    if (i >= E + N) return;
    int d = (i < E) ? dst[i] : (i - E);
    atomicAdd(&cnt[d], 1);
}

__global__ __launch_bounds__(256) void scanA(const int* __restrict__ cnt,
                                             int* __restrict__ bsum, int N) {
    __shared__ int ws[4];
    int tid = threadIdx.x, lane = tid & 63, wid = tid >> 6;
    int i0 = blockIdx.x * 1024 + tid * 4;
    int s = 0;
    if (i0 + 3 < N) {
        int4 v = *(const int4*)(cnt + i0);
        s = v.x + v.y + v.z + v.w;
    } else {
        for (int j = 0; j < 4; ++j)
            if (i0 + j < N) s += cnt[i0 + j];
    }
    #pragma unroll
    for (int o = 1; o < 64; o <<= 1) s += __shfl_xor(s, o);
    if (lane == 0) ws[wid] = s;
    __syncthreads();
    if (tid == 0) bsum[blockIdx.x] = ws[0] + ws[1] + ws[2] + ws[3];
}

__global__ __launch_bounds__(256) void scanB(int* __restrict__ bsum, int nb) {
    __shared__ int ws[4];
    int tid = threadIdx.x, lane = tid & 63, wid = tid >> 6;
    int v = (tid < nb) ? bsum[tid] : 0;
    int incl = v;
    #pragma unroll
    for (int o = 1; o < 64; o <<= 1) {
        int t = __shfl_up(incl, o);
        if (lane >= o) incl += t;
    }
    if (lane == 63) ws[wid] = incl;
    __syncthreads();
    int add = 0;
    for (int w = 0; w < wid; ++w) add += ws[w];
    if (tid < nb) bsum[tid] = add + incl - v;
}

__global__ __launch_bounds__(256) void scanC(const int* __restrict__ cnt,
                                             const int* __restrict__ bsum,
                                             int* __restrict__ rp, int* __restrict__ wofs, int N) {
    __shared__ int ws[4];
    __shared__ int base_s;
    int tid = threadIdx.x, lane = tid & 63, wid = tid >> 6;
    int i0 = blockIdx.x * 1024 + tid * 4;
    int v0 = (i0 + 0 < N) ? cnt[i0 + 0] : 0;
    int v1 = (i0 + 1 < N) ? cnt[i0 + 1] : 0;
    int v2 = (i0 + 2 < N) ? cnt[i0 + 2] : 0;
    int v3 = (i0 + 3 < N) ? cnt[i0 + 3] : 0;
    int t4 = v0 + v1 + v2 + v3;
    int incl = t4;
    #pragma unroll
    for (int o = 1; o < 64; o <<= 1) {
        int t = __shfl_up(incl, o);
        if (lane >= o) incl += t;
    }
    if (lane == 63) ws[wid] = incl;
    if (tid == 0) base_s = bsum[blockIdx.x];
    __syncthreads();
    int wadd = 0;
    for (int w = 0; w < wid; ++w) wadd += ws[w];
    int pre = base_s + wadd + incl - t4;
    int p1 = pre + v0, p2 = p1 + v1, p3 = p2 + v2, p4 = p3 + v3;
    if (i0 + 0 < N) { wofs[i0 + 0] = pre; rp[i0 + 1] = p1; }
    if (i0 + 1 < N) { wofs[i0 + 1] = p1;  rp[i0 + 2] = p2; }
    if (i0 + 2 < N) { wofs[i0 + 2] = p2;  rp[i0 + 3] = p3; }
    if (i0 + 3 < N) { wofs[i0 + 3] = p3;  rp[i0 + 4] = p4; }
    if (blockIdx.x == 0 && tid == 0) rp[0] = 0;
}

__global__ void scatter_kernel(const int* __restrict__ src, const int* __restrict__ dst,
                               int E, int N, int* __restrict__ wofs, int* __restrict__ sorted_src) {
    int i = blockIdx.x * blockDim.x + threadIdx.x;
    if (i >= E + N) return;
    int d, s;
    if (i < E) { d = dst[i]; s = src[i]; } else { d = i - E; s = d; }
    int pos = atomicAdd(&wofs[d], 1);
    sorted_src[pos] = s;
}

// ---------------- MFMA GEMM on packed inputs ----------------

__device__ __forceinline__ void gll16(const f16* g, f16* l) {
#if __has_builtin(__builtin_amdgcn_global_load_lds)
    __builtin_amdgcn_global_load_lds((const __attribute__((address_space(1))) void*)g,
                                     (__attribute__((address_space(3))) void*)l, 16, 0, 0);
#else
    *(f16x8*)l = *(const f16x8*)g;
#endif
}

__global__ __launch_bounds__(256) void gemm16_packed(
    const f16* __restrict__ PA, int N, int K,
    const f16* __restrict__ PBl, const f16* __restrict__ PBr,
    f16* __restrict__ Cl, f16* __restrict__ Cr) {
    __shared__ f16 lds[2][2][8192];  // 64KB
    const int nblk = gridDim.x;
    int bid = blockIdx.x;
    int xcd = bid & 7, jj = bid >> 3;
    int nper = nblk >> 3, rem = nblk & 7;
    int slot = (xcd < rem) ? xcd * (nper + 1) + jj
                           : rem * (nper + 1) + (xcd - rem) * nper + jj;
    int R = slot >> 2, by = slot & 3;
    const f16* __restrict__ PB = (by >> 1) ? PBr : PBl;
    f16* __restrict__ C = (by >> 1) ? Cr : Cl;
    const int cb = by & 1;
    const int row0 = R * 128;
    const int col0 = cb * 128;
    const f16* Abase = PA + (size_t)R * 128 * K;
    const f16* Bbase = PB + (size_t)cb * 128 * K;
    const int t = threadIdx.x;
    const int lane = t & 63, wid = t >> 6;
    const int wr = (wid >> 1) * 64, wc = (wid & 1) * 64;
    const int lg = lane >> 4, lr = lane & 15;

    f32x4 acc[4][4];
    #pragma unroll
    for (int m = 0; m < 4; ++m)
        #pragma unroll
        for (int n = 0; n < 4; ++n) acc[m][n] = (f32x4){0.f, 0.f, 0.f, 0.f};

    auto stage = [&](int buf, int k0) {
        const f16* As = Abase + (size_t)k0 * 128 + t * 8;
        const f16* Bs = Bbase + (size_t)k0 * 128 + t * 8;
        f16* Al = &lds[buf][0][t * 8];
        f16* Bl = &lds[buf][1][t * 8];
        #pragma unroll
        for (int u = 0; u < 4; ++u) gll16(As + u * 2048, Al + u * 2048);
        #pragma unroll
        for (int u = 0; u < 4; ++u) gll16(Bs + u * 2048, Bl + u * 2048);
    };

    const int nk = K >> 6;
    stage(0, 0);
    asm volatile("s_waitcnt vmcnt(0)" ::: "memory");
    __syncthreads();
    for (int c = 0; c < nk; ++c) {
        if (c + 1 < nk) stage((c + 1) & 1, (c + 1) * 64);
        f16x8* Asp = (f16x8*)lds[c & 1][0];
        f16x8* Bsp = (f16x8*)lds[c & 1][1];
        #pragma unroll
        for (int s = 0; s < 2; ++s) {
            f16x8 af[4], bf[4];
            #pragma unroll
            for (int m = 0; m < 4; ++m) af[m] = Asp[(s * 4 + lg) * 128 + wr + m * 16 + lr];
            #pragma unroll
            for (int n = 0; n < 4; ++n) bf[n] = Bsp[(s * 4 + lg) * 128 + wc + n * 16 + lr];
            #pragma unroll
            for (int m = 0; m < 4; ++m)
                #pragma unroll
                for (int n = 0; n < 4; ++n)
                    acc[m][n] = __builtin_amdgcn_mfma_f32_16x16x32_f16(af[m], bf[n], acc[m][n], 0, 0, 0);
        }
        asm volatile("s_waitcnt vmcnt(0)" ::: "memory");
        __syncthreads();
    }
    #pragma unroll
    for (int m = 0; m < 4; ++m) {
        int row_b = row0 + wr + m * 16 + lg * 4;
        #pragma unroll
        for (int reg = 0; reg < 4; ++reg) {
            int row = row_b + reg;
            if (row < N) {
                #pragma unroll
                for (int n = 0; n < 4; ++n)
                    C[(size_t)row * 256 + col0 + wc + n * 16 + lr] = (f16)acc[m][n][reg];
            }
        }
    }
}

// ---------------- small GEMM layer 4 ----------------

__global__ __launch_bounds__(256) void gemm_small16(
    const f16* __restrict__ A, int N,
    const float* __restrict__ Wl, const float* __restrict__ Wr,
    float* __restrict__ Cl, float* __restrict__ Cr) {
    const int K = 256, M = 16;
    __shared__ float As[16][260];
    __shared__ float Ws[256 * 16];
    const float* __restrict__ W = (blockIdx.y == 0) ? Wl : Wr;
    float* __restrict__ C = (blockIdx.y == 0) ? Cl : Cr;
    int row0 = blockIdx.x * 16;
    int tid = threadIdx.x;
    {
        #pragma unroll
        for (int u = 0; u < 4; ++u)
            *(float4*)&Ws[tid * 16 + u * 4] = *(const float4*)(W + tid * 16 + u * 4);
        int r = tid >> 4;
        int c = (tid & 15) * 16;
        int row = row0 + r;
        if (row < N) {
            int R = row >> 7, rr = row & 127;
            const f16* base = A + ((size_t)(R * 32 + (c >> 3)) * 128 + rr) * 8;
            f16x8 v0 = *(const f16x8*)base;
            f16x8 v1 = *(const f16x8*)(base + 1024);
            #pragma unroll
            for (int j = 0; j < 8; ++j) {
                As[r][c + j] = (float)v0[j];
                As[r][c + 8 + j] = (float)v1[j];
            }
        } else {
            #pragma unroll
            for (int j = 0; j < 16; ++j) As[r][c + j] = 0.f;
        }
    }
    __syncthreads();
    int r = tid >> 4;
    int col = tid & 15;
    float acc = 0.f;
    #pragma unroll 8
    for (int k = 0; k < K; ++k) acc = fmaf(As[r][k], Ws[k * M + col], acc);
    int row = row0 + r;
    if (row < N) C[(size_t)row * M + col] = acc;
}

// ---------------- edge kernel, H=8 D=32: two nodes/wave, 2-edge unrolled ----------------

__global__ __launch_bounds__(256) void edge_h8_f16(
    const f16* __restrict__ xl, const f16* __restrict__ xr,
    const int* __restrict__ rp, const int* __restrict__ ss,
    const float* __restrict__ att, const float* __restrict__ bias,
    f16* __restrict__ hout, int N) {
    int tid = threadIdx.x;
    int half = tid >> 5;
    int hl = tid & 31;
    int n = blockIdx.x * 8 + half;
    if (n >= N) return;
    const int HD = 256;
    f16x8 xrr = *(const f16x8*)(xr + (size_t)n * HD + hl * 8);
    float4 atlo = *(const float4*)(att + hl * 8);
    float4 athi = *(const float4*)(att + hl * 8 + 4);
    f16x2 at01 = {(f16)atlo.x, (f16)atlo.y};
    f16x2 at23 = {(f16)atlo.z, (f16)atlo.w};
    f16x2 at45 = {(f16)athi.x, (f16)athi.y};
    f16x2 at67 = {(f16)athi.z, (f16)athi.w};
    const f16 ns = (f16)NEG_SLOPE;
    float m = -INFINITY, s = 0.f;
    float a[8];
    #pragma unroll
    for (int j = 0; j < 8; ++j) a[j] = 0.f;
    int beg = rp[n], end = rp[n + 1];
    int last = end - 1;
    const f16* xb = xl + hl * 8;
    // prefetch window: 4 data rows + 2 indices ahead
    f16x8 r0 = *(const f16x8*)(xb + (size_t)ss[beg] * HD);
    f16x8 r1 = *(const f16x8*)(xb + (size_t)ss[min(beg + 1, last)] * HD);
    f16x8 r2 = *(const f16x8*)(xb + (size_t)ss[min(beg + 2, last)] * HD);
    f16x8 r3 = *(const f16x8*)(xb + (size_t)ss[min(beg + 3, last)] * HD);
    int j4 = ss[min(beg + 4, last)];
    int j5 = ss[min(beg + 5, last)];

    auto score = [&](const f16x8& cur) -> float {
        f16x8 g = cur + xrr;
        f16x8 gs = g * ns;
        f16x8 lk = __builtin_elementwise_max(g, gs);
#if __has_builtin(__builtin_amdgcn_fdot2)
        f16x2 l01 = __builtin_shufflevector(lk, lk, 0, 1);
        f16x2 l23 = __builtin_shufflevector(lk, lk, 2, 3);
        f16x2 l45 = __builtin_shufflevector(lk, lk, 4, 5);
        f16x2 l67 = __builtin_shufflevector(lk, lk, 6, 7);
        float p = __builtin_amdgcn_fdot2(l01, at01, 0.f, false);
        p = __builtin_amdgcn_fdot2(l23, at23, p, false);
        p = __builtin_amdgcn_fdot2(l45, at45, p, false);
        p = __builtin_amdgcn_fdot2(l67, at67, p, false);
#else
        float p = (float)lk[0] * atlo.x + (float)lk[1] * atlo.y +
                  (float)lk[2] * atlo.z + (float)lk[3] * atlo.w +
                  (float)lk[4] * athi.x + (float)lk[5] * athi.y +
                  (float)lk[6] * athi.z + (float)lk[7] * athi.w;
#endif
        return p;
    };

    int i = beg;
    for (; i + 1 < end; i += 2) {
        f16x8 c0 = r0, c1 = r1;
        r0 = r2; r1 = r3;
        r2 = *(const f16x8*)(xb + (size_t)j4 * HD);
        r3 = *(const f16x8*)(xb + (size_t)j5 * HD);
        j4 = ss[min(i + 6, last)];
        j5 = ss[min(i + 7, last)];
        float p0 = score(c0);
        float p1 = score(c1);
        p0 += __shfl_xor(p0, 1);
        p1 += __shfl_xor(p1, 1);
        p0 += __shfl_xor(p0, 2);
        p1 += __shfl_xor(p1, 2);
        float d0 = p0 - m, d1 = p1 - m;
        if (__any(fmaxf(d0, d1) > 8.f)) {
            float mn = fmaxf(m, fmaxf(p0, p1));
            float cf = __expf(m - mn);  // exp(-inf)=0 handles init
            s *= cf;
            #pragma unroll
            for (int j = 0; j < 8; ++j) a[j] *= cf;
            m = mn;
            d0 = p0 - m; d1 = p1 - m;
        }
        float e0 = __expf(d0);
        float e1 = __expf(d1);
        s += e0 + e1;
        #pragma unroll
        for (int j = 0; j < 8; ++j)
            a[j] = fmaf(e1, (float)c1[j], fmaf(e0, (float)c0[j], a[j]));
    }
    if (i < end) {  // odd tail
        f16x8 c0 = r0;
        float p0 = score(c0);
        p0 += __shfl_xor(p0, 1);
        p0 += __shfl_xor(p0, 2);
        float d0 = p0 - m;
        if (__any(d0 > 8.f)) {
            float mn = fmaxf(m, p0);
            float cf = __expf(m - mn);
            s *= cf;
            #pragma unroll
            for (int j = 0; j < 8; ++j) a[j] *= cf;
            m = mn;
            d0 = p0 - m;
        }
        float e0 = __expf(d0);
        s += e0;
        #pragma unroll
        for (int j = 0; j < 8; ++j) a[j] = fmaf(e0, (float)c0[j], a[j]);
    }
    float inv = 1.f / (s + 1e-16f);
    float4 blo = *(const float4*)(bias + hl * 8);
    float4 bhi = *(const float4*)(bias + hl * 8 + 4);
    float o[8];
    o[0] = a[0] * inv + blo.x; o[1] = a[1] * inv + blo.y;
    o[2] = a[2] * inv + blo.z; o[3] = a[3] * inv + blo.w;
    o[4] = a[4] * inv + bhi.x; o[5] = a[5] * inv + bhi.y;
    o[6] = a[6] * inv + bhi.z; o[7] = a[7] * inv + bhi.w;
    f16x8 ov;
    #pragma unroll
    for (int j = 0; j < 8; ++j) {
        float e = o[j] > 0.f ? o[j] : __expf(o[j]) - 1.f;
        ov[j] = (f16)e;
    }
    *(f16x8*)(hout + ((size_t)((n >> 7) * 32 + hl) * 128 + (n & 127)) * 8) = ov;
}

// ---------------- edge kernel layer 4: four nodes/wave, 2-edge unrolled ----------------

__global__ __launch_bounds__(256) void edge_h1_kernel(
    const float* __restrict__ xl, const float* __restrict__ xr,
    const int* __restrict__ rp, const int* __restrict__ ss,
    const float* __restrict__ att, const float* __restrict__ bias,
    float* __restrict__ out, int N) {
    int tid = threadIdx.x;
    int grp = tid >> 4;
    int gl = tid & 15;
    int n = blockIdx.x * 16 + grp;
    if (n >= N) return;
    float xrv = xr[(size_t)n * 16 + gl];
    float attv = att[gl];
    float bv = bias[gl];
    float m = -INFINITY, s = 0.f, acc = 0.f;
    int beg = rp[n], end = rp[n + 1], last = end - 1;
    const float* xb = xl + gl;
    float x0 = xb[(size_t)ss[beg] * 16];
    float x1 = xb[(size_t)ss[min(beg + 1, last)] * 16];
    float x2 = xb[(size_t)ss[min(beg + 2, last)] * 16];
    float x3 = xb[(size_t)ss[min(beg + 3, last)] * 16];
    int j4 = ss[min(beg + 4, last)];
    int j5 = ss[min(beg + 5, last)];
    int i = beg;
    for (; i + 1 < end; i += 2) {
        float c0 = x0, c1 = x1;
        x0 = x2; x1 = x3;
        x2 = xb[(size_t)j4 * 16];
        x3 = xb[(size_t)j5 * 16];
        j4 = ss[min(i + 6, last)];
        j5 = ss[min(i + 7, last)];
        float g0 = c0 + xrv, g1 = c1 + xrv;
        float p0 = attv * fmaxf(g0, NEG_SLOPE * g0);
        float p1 = attv * fmaxf(g1, NEG_SLOPE * g1);
        p0 += __shfl_xor(p0, 1); p1 += __shfl_xor(p1, 1);
        p0 += __shfl_xor(p0, 2); p1 += __shfl_xor(p1, 2);
        p0 += __shfl_xor(p0, 4); p1 += __shfl_xor(p1, 4);
        p0 += __shfl_xor(p0, 8); p1 += __shfl_xor(p1, 8);
        float d0 = p0 - m, d1 = p1 - m;
        if (__any(fmaxf(d0, d1) > 8.f)) {
            float mn = fmaxf(m, fmaxf(p0, p1));
            float cf = __expf(m - mn);
            s *= cf; acc *= cf;
            m = mn;
            d0 = p0 - m; d1 = p1 - m;
        }
        float e0 = __expf(d0), e1 = __expf(d1);
        s += e0 + e1;
        acc = fmaf(e1, c1, fmaf(e0, c0, acc));
    }
    if (i < end) {
        float c0 = x0;
        float g0 = c0 + xrv;
        float p0 = attv * fmaxf(g0, NEG_SLOPE * g0);
        p0 += __shfl_xor(p0, 1);
        p0 += __shfl_xor(p0, 2);
        p0 += __shfl_xor(p0, 4);
        p0 += __shfl_xor(p0, 8);
        float d0 = p0 - m;
        if (__any(d0 > 8.f)) {
            float mn = fmaxf(m, p0);
            float cf = __expf(m - mn);
            s *= cf; acc *= cf;
            m = mn;
            d0 = p0 - m;
        }
        float e0 = __expf(d0);
        s += e0;
        acc = fmaf(e0, c0, acc);
    }
    float v = acc / (s + 1e-16f) + bv;
    float mx = v;
    mx = fmaxf(mx, __shfl_xor(mx, 1));
    mx = fmaxf(mx, __shfl_xor(mx, 2));
    mx = fmaxf(mx, __shfl_xor(mx, 4));
    mx = fmaxf(mx, __shfl_xor(mx, 8));
    float ex = __expf(v - mx);
    float se = ex;
    se += __shfl_xor(se, 1);
    se += __shfl_xor(se, 2);
    se += __shfl_xor(se, 4);
    se += __shfl_xor(se, 8);
    out[(size_t)n * 16 + gl] = v - mx - __logf(se);
}

// ---------------- launch ----------------

extern "C" void kernel_launch(void* const* d_in, const int* in_sizes, int n_in,
                              void* d_out, int out_size, void* d_ws, size_t ws_size,
                              hipStream_t stream) {
    const float* x    = (const float*)d_in[0];
    const int*   ei   = (const int*)d_in[1];
    const float* Wl1  = (const float*)d_in[2];
    const float* Wr1  = (const float*)d_in[3];
    const float* att1 = (const float*)d_in[4];
    const float* b1   = (const float*)d_in[5];
    const float* Wl2  = (const float*)d_in[6];
    const float* Wr2  = (const float*)d_in[7];
    const float* att2 = (const float*)d_in[8];
    const float* b2   = (const float*)d_in[9];
    const float* Wl3  = (const float*)d_in[10];
    const float* Wr3  = (const float*)d_in[11];
    const float* att3 = (const float*)d_in[12];
    const float* b3   = (const float*)d_in[13];
    const float* Wl4  = (const float*)d_in[14];
    const float* Wr4  = (const float*)d_in[15];
    const float* att4 = (const float*)d_in[16];
    const float* b4   = (const float*)d_in[17];

    const int N = in_sizes[0] / 128;
    const int E = in_sizes[1] / 2;
    const int* src = ei;
    const int* dst = ei + E;
    const int Etot = E + N;
    const int ntile = idiv(N, 128);

    char* wsb = (char*)d_ws;
    size_t off = 0;
    auto alloc = [&](size_t bytes) -> void* {
        void* p = wsb + off;
        off += (bytes + 255) & ~(size_t)255;
        return p;
    };
    f16*   PX   = (f16*)alloc((size_t)ntile * 128 * 128 * 2);
    f16*   PH   = (f16*)alloc((size_t)ntile * 128 * 256 * 2);
    f16*   xl16 = (f16*)alloc((size_t)N * 256 * 2);
    f16*   xr16 = (f16*)alloc((size_t)N * 256 * 2);
    float* xl4  = (float*)alloc((size_t)N * 16 * 4);
    float* xr4  = (float*)alloc((size_t)N * 16 * 4);
    f16*   PB1l = (f16*)alloc((size_t)256 * 128 * 2);
    f16*   PB1r = (f16*)alloc((size_t)256 * 128 * 2);
    f16*   PB2l = (f16*)alloc((size_t)256 * 256 * 2);
    f16*   PB2r = (f16*)alloc((size_t)256 * 256 * 2);
    f16*   PB3l = (f16*)alloc((size_t)256 * 256 * 2);
    f16*   PB3r = (f16*)alloc((size_t)256 * 256 * 2);
    int*   cnt  = (int*)alloc((size_t)N * 4);
    int*   wof  = (int*)alloc((size_t)N * 4);
    int*   rp   = (int*)alloc((size_t)(N + 1) * 4);
    int*   ss   = (int*)alloc((size_t)Etot * 4);
    int*   bsum = (int*)alloc((size_t)idiv(N, 1024) * 4);

    // conversions
    conv_x_packed<<<ntile, 256, 0, stream>>>(x, PX, N);
    convT_all<<<dim3(8, 8, 6), 256, 0, stream>>>(Wl1, Wr1, Wl2, Wr2, Wl3, Wr3,
                                                 PB1l, PB1r, PB2l, PB2r, PB3l, PB3r);

    // CSR build
    hipMemsetAsync(cnt, 0, (size_t)N * 4, stream);
    hist_kernel<<<idiv(Etot, 256), 256, 0, stream>>>(dst, E, N, cnt);
    const int nb = idiv(N, 1024);
    scanA<<<nb, 256, 0, stream>>>(cnt, bsum, N);
    scanB<<<1, 256, 0, stream>>>(bsum, nb);
    scanC<<<nb, 256, 0, stream>>>(cnt, bsum, rp, wof, N);
    scatter_kernel<<<idiv(Etot, 256), 256, 0, stream>>>(src, dst, E, N, wof, ss);

    const int nblk = ntile * 4;
    // layer 1 (K=128)
    gemm16_packed<<<nblk, 256, 0, stream>>>(PX, N, 128, PB1l, PB1r, xl16, xr16);
    edge_h8_f16<<<idiv(N, 8), 256, 0, stream>>>(xl16, xr16, rp, ss, att1, b1, PH, N);
    // layer 2
    gemm16_packed<<<nblk, 256, 0, stream>>>(PH, N, 256, PB2l, PB2r, xl16, xr16);
    edge_h8_f16<<<idiv(N, 8), 256, 0, stream>>>(xl16, xr16, rp, ss, att2, b2, PH, N);
    // layer 3
    gemm16_packed<<<nblk, 256, 0, stream>>>(PH, N, 256, PB3l, PB3r, xl16, xr16);
    edge_h8_f16<<<idiv(N, 8), 256, 0, stream>>>(xl16, xr16, rp, ss, att3, b3, PH, N);
    // layer 4 (M=16) + fused log_softmax
    gemm_small16<<<dim3(idiv(N, 16), 2), 256, 0, stream>>>(PH, N, Wl4, Wr4, xl4, xr4);
    edge_h1_kernel<<<idiv(N, 16), 256, 0, stream>>>(xl4, xr4, rp, ss, att4, b4, (float*)d_out, N);
}